// Round 5
// baseline (967.793 us; speedup 1.0000x reference)
//
#include <hip/hip_runtime.h>
#include <math.h>

// Problem constants (match reference)
#define NN 150000
#define NE 2400000
#define NG 1024
#define DIN 6
#define DH 32
#define DB 16
#define BN_EPS 1e-5f

#define MLP_BLOCKS ((NN + 255) / 256)   // 586  (layer-1 mlp)
#define FUSED_BLOCKS ((NN + 31) / 32)   // 4688 (fused layers 2/3)

// bucket sort params
#define NB 512            // buckets
#define NPB 293           // nodes per bucket (512*293 = 150016 >= NN)
#define SCH 4096          // edges per scatter block
#define EPB 16            // edges per thread in scatter
#define CAP 8192          // max edges per bucket (expected ~4690)
#define NSCAT ((NE + SCH - 1) / SCH)  // 586

// inclusive Hillis-Steele scan of 512 ints in LDS with 256 threads
#define SCAN512(scarr, t)                                     \
    for (int off = 1; off < 512; off <<= 1) {                 \
        int v0 = (t >= off) ? scarr[t - off] : 0;             \
        int v1 = scarr[t + 256 - off];                        \
        __syncthreads();                                      \
        if (t >= off) scarr[t] += v0;                         \
        scarr[t + 256] += v1;                                 \
        __syncthreads();                                      \
    }

// ================= bucket CSR build =================
__global__ void bucket_count(const int* __restrict__ ei, int* __restrict__ bcnt) {
    __shared__ int hist[NB];
    int t = threadIdx.x;
    for (int i = t; i < NB; i += 256) hist[i] = 0;
    __syncthreads();
    long e0 = (long)blockIdx.x * SCH;
#pragma unroll
    for (int k = 0; k < EPB; ++k) {
        long idx = e0 + k * 256 + t;
        if (idx < NE) atomicAdd(&hist[ei[NE + idx] / NPB], 1);
    }
    __syncthreads();
    for (int i = t; i < NB; i += 256)
        if (hist[i]) atomicAdd(&bcnt[i], hist[i]);
}

__global__ void bucket_scan(const int* __restrict__ bcnt,
                            int* __restrict__ bbase, int* __restrict__ bcur) {
    __shared__ int sc[NB];
    int t = threadIdx.x;
    int c0 = bcnt[t], c1 = bcnt[t + 256];
    sc[t] = c0; sc[t + 256] = c1;
    __syncthreads();
    SCAN512(sc, t);
    int e0 = sc[t] - c0, e1 = sc[t + 256] - c1;
    bbase[t] = e0; bbase[t + 256] = e1;
    bcur[t] = e0;  bcur[t + 256] = e1;
    if (t == 0) bbase[NB] = NE;
}

// block-local binning -> semi-coalesced (src,dst) writes into bucket regions
__global__ void bucket_scatter(const int* __restrict__ ei, int* __restrict__ bcur,
                               uint2* __restrict__ ebuf) {
    __shared__ int hist[NB];
    __shared__ int sc[NB];
    __shared__ int lcur[NB];
    __shared__ int gbase[NB];
    __shared__ uint2 stage[SCH];
    int t = threadIdx.x;
    long e0 = (long)blockIdx.x * SCH;
    int s16[EPB], d16[EPB];
    for (int i = t; i < NB; i += 256) hist[i] = 0;
    __syncthreads();
#pragma unroll
    for (int k = 0; k < EPB; ++k) {
        long idx = e0 + k * 256 + t;
        if (idx < NE) {
            s16[k] = ei[idx];
            d16[k] = ei[NE + idx];
            atomicAdd(&hist[d16[k] / NPB], 1);
        } else d16[k] = -1;
    }
    __syncthreads();
    for (int i = t; i < NB; i += 256) sc[i] = hist[i];
    __syncthreads();
    SCAN512(sc, t);
    for (int i = t; i < NB; i += 256) lcur[i] = sc[i] - hist[i];
    __syncthreads();
#pragma unroll
    for (int k = 0; k < EPB; ++k) {
        if (d16[k] >= 0) {
            int b = d16[k] / NPB;
            int p = atomicAdd(&lcur[b], 1);
            stage[p] = make_uint2((unsigned)s16[k], (unsigned)d16[k]);
        }
    }
    __syncthreads();
    for (int i = t; i < NB; i += 256) {
        int h = hist[i];
        gbase[i] = h ? atomicAdd(&bcur[i], h) : 0;
    }
    __syncthreads();
    int cnt = (int)((NE - e0) < SCH ? (NE - e0) : SCH);
    for (int i = t; i < cnt; i += 256) {
        uint2 ed = stage[i];
        int b = (int)ed.y / NPB;
        ebuf[gbase[b] + (i - (sc[b] - hist[b]))] = ed;
    }
}

// per-bucket LDS counting sort -> csr_src + row_ptr (fully coalesced global I/O)
__global__ void bucket_sort(const uint2* __restrict__ ebuf, const int* __restrict__ bbase,
                            int* __restrict__ row_ptr, int* __restrict__ csr_src) {
    __shared__ int deg[NB];
    __shared__ int sc[NB];
    __shared__ int cur[NB];
    __shared__ int srcbuf[CAP];
    int b = blockIdx.x, t = threadIdx.x;
    int node0 = b * NPB;
    int nlocal = (NN - node0) < NPB ? (NN - node0) : NPB;
    int ebase = bbase[b];
    int ecnt = bbase[b + 1] - ebase;
    if (ecnt > CAP) ecnt = CAP;
    for (int i = t; i < NB; i += 256) deg[i] = 0;
    __syncthreads();
    for (int i = t; i < ecnt; i += 256) {
        int d = (int)ebuf[ebase + i].y - node0;
        atomicAdd(&deg[d], 1);
    }
    __syncthreads();
    for (int i = t; i < NB; i += 256) sc[i] = deg[i];
    __syncthreads();
    SCAN512(sc, t);
    for (int j = t; j < nlocal; j += 256) {
        int st = sc[j] - deg[j];
        row_ptr[node0 + j] = ebase + st;
        cur[j] = st;
    }
    if (b == NB - 1 && t == 0) row_ptr[NN] = NE;
    __syncthreads();
    for (int i = t; i < ecnt; i += 256) {
        uint2 ed = ebuf[ebase + i];
        int d = (int)ed.y - node0;
        int p = atomicAdd(&cur[d], 1);
        srcbuf[p] = (int)ed.x;
    }
    __syncthreads();
    for (int i = t; i < ecnt; i += 256) csr_src[ebase + i] = srcbuf[i];
}

// ======= graph boundaries via binary search (batch is sorted) =======
__global__ void gbounds(const int* __restrict__ bat, int* __restrict__ gptr) {
    int g = blockIdx.x * blockDim.x + threadIdx.x;
    if (g > NG) return;
    int lo = 0, hi = NN;
    while (lo < hi) {
        int mid = (lo + hi) >> 1;
        if (bat[mid] < g) lo = mid + 1; else hi = mid;
    }
    gptr[g] = lo;
}

// ================= layer 1: gather (6ch) =================
__global__ void gather6(const int* __restrict__ row_ptr, const int* __restrict__ csr_src,
                        const float* __restrict__ x, float* __restrict__ agg) {
    int node = blockIdx.x * blockDim.x + threadIdx.x;
    if (node >= NN) return;
    int beg = row_ptr[node], end = row_ptr[node + 1];
    const float2* xs = (const float2*)(x + (long)node * DIN);
    float2 a0 = xs[0], a1 = xs[1], a2 = xs[2];   // self term
    for (int e = beg; e < end; ++e) {
        int s = csr_src[e];
        const float2* p = (const float2*)(x + (long)s * DIN);
        float2 b0 = p[0], b1 = p[1], b2 = p[2];
        a0.x += b0.x; a0.y += b0.y;
        a1.x += b1.x; a1.y += b1.y;
        a2.x += b2.x; a2.y += b2.y;
    }
    float2* o = (float2*)(agg + (long)node * DIN);
    o[0] = a0; o[1] = a1; o[2] = a2;
}

// ======== layer 1 MLP + relu + BN-stat partials ========
template <int IN>
__global__ void mlp_stats(const float* __restrict__ agg,
                          float* __restrict__ out,
                          const float* __restrict__ w1, const float* __restrict__ b1,
                          const float* __restrict__ w2, const float* __restrict__ b2,
                          float* __restrict__ partial /* [gridDim][64] */) {
    __shared__ float sw1[IN * DH];
    __shared__ float sw2[DH * DH];
    __shared__ float sb1[DH];
    __shared__ float sb2[DH];
    __shared__ float bsum[DH];
    __shared__ float bsq[DH];
    int t = threadIdx.x;
    for (int i = t; i < IN * DH; i += blockDim.x) sw1[i] = w1[i];
    for (int i = t; i < DH * DH; i += blockDim.x) sw2[i] = w2[i];
    if (t < DH) { sb1[t] = b1[t]; sb2[t] = b2[t]; bsum[t] = 0.f; bsq[t] = 0.f; }
    __syncthreads();

    int node = blockIdx.x * blockDim.x + t;
    bool valid = node < NN;

    float a[IN];
    if (valid) {
        const float* ar = agg + (long)node * IN;
#pragma unroll
        for (int k = 0; k < IN; ++k) a[k] = ar[k];
    } else {
#pragma unroll
        for (int k = 0; k < IN; ++k) a[k] = 0.f;
    }

    float u[DH];
#pragma unroll
    for (int j = 0; j < DH; ++j) {
        float acc = sb1[j];
#pragma unroll
        for (int k = 0; k < IN; ++k) acc += a[k] * sw1[k * DH + j];
        u[j] = fmaxf(acc, 0.f);
    }

    float r[DH];
#pragma unroll
    for (int j = 0; j < DH; ++j) {
        float acc = sb2[j];
#pragma unroll
        for (int k = 0; k < DH; ++k) acc += u[k] * sw2[k * DH + j];
        r[j] = valid ? fmaxf(acc, 0.f) : 0.f;
    }

    if (valid) {
        float4* o = (float4*)(out + (long)node * DH);
#pragma unroll
        for (int q = 0; q < DH / 4; ++q)
            o[q] = make_float4(r[4 * q], r[4 * q + 1], r[4 * q + 2], r[4 * q + 3]);
    }

    int lane = t & 63;
#pragma unroll
    for (int j = 0; j < DH; ++j) {
        float s = r[j];
        float q = r[j] * r[j];
        for (int o = 32; o > 0; o >>= 1) {
            s += __shfl_xor(s, o);
            q += __shfl_xor(q, o);
        }
        if (lane == 0) {
            atomicAdd(&bsum[j], s);   // LDS atomic, cheap
            atomicAdd(&bsq[j], q);
        }
    }
    __syncthreads();
    if (t < 2 * DH) {
        float v = (t < DH) ? bsum[t] : bsq[t - DH];
        partial[(long)blockIdx.x * (2 * DH) + t] = v;
    }
}

// ======== fused layers 2/3: gather(BN-affine folded) + MLP + stats ========
// 32 nodes / block, 8 threads / node. h (input) and out MUST be different buffers.
__global__ void __launch_bounds__(256) fused_gin32(
    const int* __restrict__ row_ptr, const int* __restrict__ csr_src,
    const float* __restrict__ h, const float* __restrict__ ss,
    const float* __restrict__ w1, const float* __restrict__ b1,
    const float* __restrict__ w2, const float* __restrict__ b2,
    float* __restrict__ out, float* __restrict__ partial /* [gridDim][64] */) {
    __shared__ float sw1[DH * DH];
    __shared__ float sw2[DH * DH];
    __shared__ float sb1[DH];
    __shared__ float sb2[DH];
    __shared__ float sagg[32][DH + 1];
    __shared__ float su[32][DH + 1];
    __shared__ float bsum[DH];
    __shared__ float bsq[DH];
    int t = threadIdx.x;
    for (int i = t; i < DH * DH; i += 256) { sw1[i] = w1[i]; sw2[i] = w2[i]; }
    if (t < DH) { sb1[t] = b1[t]; sb2[t] = b2[t]; bsum[t] = 0.f; bsq[t] = 0.f; }

    int nl = t >> 3, sub = t & 7;
    int node = blockIdx.x * 32 + nl;
    bool valid = node < NN;

    // ---- gather (8 threads/node, float4 each) + affine fold ----
    float4 acc = make_float4(0.f, 0.f, 0.f, 0.f);
    int beg = 0, end = 0;
    if (valid) {
        beg = row_ptr[node];
        end = row_ptr[node + 1];
        acc = *((const float4*)(h + (long)node * DH) + sub);
    }
    for (int e = beg; e < end; ++e) {
        int s = csr_src[e];
        float4 v = *((const float4*)(h + (long)s * DH) + sub);
        acc.x += v.x; acc.y += v.y; acc.z += v.z; acc.w += v.w;
    }
    float cnt = (float)(end - beg + 1);
    float4 scv = ((const float4*)ss)[sub];
    float4 shv = ((const float4*)(ss + DH))[sub];
    sagg[nl][sub * 4 + 0] = acc.x * scv.x + cnt * shv.x;
    sagg[nl][sub * 4 + 1] = acc.y * scv.y + cnt * shv.y;
    sagg[nl][sub * 4 + 2] = acc.z * scv.z + cnt * shv.z;
    sagg[nl][sub * 4 + 3] = acc.w * scv.w + cnt * shv.w;
    __syncthreads();

    // ---- MLP layer A: each thread computes 4 of 32 outputs ----
#pragma unroll
    for (int i = 0; i < 4; ++i) {
        int j = sub * 4 + i;
        float a = sb1[j];
#pragma unroll
        for (int k = 0; k < DH; ++k) a += sagg[nl][k] * sw1[k * DH + j];
        su[nl][j] = fmaxf(a, 0.f);
    }
    __syncthreads();

    // ---- MLP layer B + relu ----
    float r[4];
#pragma unroll
    for (int i = 0; i < 4; ++i) {
        int j = sub * 4 + i;
        float a = sb2[j];
#pragma unroll
        for (int k = 0; k < DH; ++k) a += su[nl][k] * sw2[k * DH + j];
        r[i] = valid ? fmaxf(a, 0.f) : 0.f;
    }
    if (valid)
        *((float4*)(out + (long)node * DH) + sub) = make_float4(r[0], r[1], r[2], r[3]);

    // ---- stats: butterfly over the 8 nodes in this wave, then LDS atomic ----
    float s0 = r[0], s1 = r[1], s2 = r[2], s3 = r[3];
    float q0 = r[0] * r[0], q1 = r[1] * r[1], q2 = r[2] * r[2], q3 = r[3] * r[3];
#pragma unroll
    for (int o = 8; o < 64; o <<= 1) {
        s0 += __shfl_xor(s0, o); s1 += __shfl_xor(s1, o);
        s2 += __shfl_xor(s2, o); s3 += __shfl_xor(s3, o);
        q0 += __shfl_xor(q0, o); q1 += __shfl_xor(q1, o);
        q2 += __shfl_xor(q2, o); q3 += __shfl_xor(q3, o);
    }
    if ((t & 63) < 8) {
        int j = sub * 4;
        atomicAdd(&bsum[j + 0], s0); atomicAdd(&bsum[j + 1], s1);
        atomicAdd(&bsum[j + 2], s2); atomicAdd(&bsum[j + 3], s3);
        atomicAdd(&bsq[j + 0], q0);  atomicAdd(&bsq[j + 1], q1);
        atomicAdd(&bsq[j + 2], q2);  atomicAdd(&bsq[j + 3], q3);
    }
    __syncthreads();
    if (t < 2 * DH) {
        float v = (t < DH) ? bsum[t] : bsq[t - DH];
        partial[(long)blockIdx.x * (2 * DH) + t] = v;
    }
}

// ===== fold partials -> BN scale/shift: ss[0..31]=sc, ss[32..63]=sh =====
__global__ void reduce_stats(const float* __restrict__ partial, int nblk,
                             const float* __restrict__ g, const float* __restrict__ be,
                             float* __restrict__ ss) {
    __shared__ float sums[2 * DH];
    int t = threadIdx.x;          // 256
    int ch = t >> 2, k0 = t & 3;
    float acc = 0.f;
    for (int k = k0; k < nblk; k += 4) acc += partial[(long)k * (2 * DH) + ch];
    acc += __shfl_xor(acc, 1);
    acc += __shfl_xor(acc, 2);
    if (k0 == 0) sums[ch] = acc;
    __syncthreads();
    if (t < DH) {
        float mu = sums[t] * (1.0f / NN);
        float var = sums[DH + t] * (1.0f / NN) - mu * mu;
        float sc = g[t] * rsqrtf(var + BN_EPS);
        ss[t] = sc;
        ss[DH + t] = be[t] - mu * sc;
    }
}

// ====== per-graph mean pool of BN(h), affine folded: sc*mean(h)+sh ======
__global__ void pool2_aff(const float* __restrict__ h, const int* __restrict__ gptr,
                          const float* __restrict__ ss, float* __restrict__ emb) {
    int g = blockIdx.x;
    int t = threadIdx.x;           // 64 threads
    int beg = gptr[g], end = gptr[g + 1];
    int d = t & 31, half = t >> 5;
    float acc = 0.f;
    for (int n = beg + half; n < end; n += 2) acc += h[(long)n * DH + d];
    acc += __shfl_xor(acc, 32);
    if (t < 32) {
        int c = end - beg;
        float val = 0.f;
        if (c > 0) val = ss[d] * (acc / (float)c) + ss[DH + d];
        emb[(long)g * DH + d] = val;
    }
}

// ================= head: emb -> 16 relu -> 1 sigmoid =================
__global__ void head_kernel(const float* __restrict__ emb,
                            const float* __restrict__ wb, const float* __restrict__ bb,
                            const float* __restrict__ wm, const float* __restrict__ bm,
                            float* __restrict__ out) {
    __shared__ float swb[DH * DB];
    __shared__ float sbb[DB];
    __shared__ float swm[DB];
    int t = threadIdx.x;
    for (int i = t; i < DH * DB; i += blockDim.x) swb[i] = wb[i];
    if (t < DB) { sbb[t] = bb[t]; swm[t] = wm[t]; }
    __syncthreads();

    int g = blockIdx.x * blockDim.x + t;
    if (g >= NG) return;
    float e[DH];
#pragma unroll
    for (int d = 0; d < DH; ++d) e[d] = emb[(long)g * DH + d];
    float acc = bm[0];
#pragma unroll
    for (int j = 0; j < DB; ++j) {
        float z = sbb[j];
#pragma unroll
        for (int d = 0; d < DH; ++d) z += e[d] * swb[d * DB + j];
        z = fmaxf(z, 0.f);
        acc += z * swm[j];
    }
    out[g] = 1.0f / (1.0f + expf(-acc));
}

extern "C" void kernel_launch(void* const* d_in, const int* in_sizes, int n_in,
                              void* d_out, int out_size, void* d_ws, size_t ws_size,
                              hipStream_t stream) {
    const float* x   = (const float*)d_in[0];
    const int*   ei  = (const int*)d_in[1];
    const int*   bat = (const int*)d_in[2];
    const float* w1a = (const float*)d_in[3];  const float* b1a = (const float*)d_in[4];
    const float* w1b = (const float*)d_in[5];  const float* b1b = (const float*)d_in[6];
    const float* g1  = (const float*)d_in[7];  const float* be1 = (const float*)d_in[8];
    const float* w2a = (const float*)d_in[9];  const float* b2a = (const float*)d_in[10];
    const float* w2b = (const float*)d_in[11]; const float* b2b = (const float*)d_in[12];
    const float* g2  = (const float*)d_in[13]; const float* be2 = (const float*)d_in[14];
    const float* w3a = (const float*)d_in[15]; const float* b3a = (const float*)d_in[16];
    const float* w3b = (const float*)d_in[17]; const float* b3b = (const float*)d_in[18];
    const float* g3  = (const float*)d_in[19]; const float* be3 = (const float*)d_in[20];
    const float* wb  = (const float*)d_in[21]; const float* bb  = (const float*)d_in[22];
    const float* wm  = (const float*)d_in[23]; const float* bm  = (const float*)d_in[24];
    float* out = (float*)d_out;

    // ---- workspace layout (4-byte units) ----
    char* wsb = (char*)d_ws;
    float* hbuf    = (float*)wsb;                               // NN*DH
    float* aggbuf  = hbuf + (long)NN * DH;                      // NN*DH (aliased: ebuf during CSR build; layer-1 agg; L2/L3 ping-pong)
    uint2* ebuf    = (uint2*)aggbuf;
    int*   csr_src = (int*)(aggbuf + (long)NN * DH);            // NE
    int*   row_ptr = csr_src + NE;                              // NN+1
    int*   bbase   = row_ptr + NN + 1;                          // NB+1
    int*   bcur    = bbase + NB + 1;                            // NB
    int*   gptr    = bcur + NB;                                 // NG+1
    float* emb     = (float*)(gptr + NG + 1);                   // NG*DH
    float* ss1     = emb + (long)NG * DH;                       // 64 (BN scale/shift)
    float* ss2     = ss1 + 2 * DH;                              // 64
    float* ss3     = ss2 + 2 * DH;                              // 64
    float* partial = ss3 + 2 * DH;                              // FUSED_BLOCKS*64
    int*   bcnt    = (int*)(partial + (long)FUSED_BLOCKS * 2 * DH); // NB (zeroed)

    hipMemsetAsync(bcnt, 0, (size_t)NB * 4, stream);

    const int B = 256;
    int blkN = (NN + B - 1) / B;        // == MLP_BLOCKS

    // ---- CSR via two-level bucket sort (all random access in LDS) ----
    bucket_count<<<NSCAT, B, 0, stream>>>(ei, bcnt);
    gbounds<<<(NG + 1 + B - 1) / B, B, 0, stream>>>(bat, gptr);
    bucket_scan<<<1, B, 0, stream>>>(bcnt, bbase, bcur);
    bucket_scatter<<<NSCAT, B, 0, stream>>>(ei, bcur, ebuf);
    bucket_sort<<<NB, B, 0, stream>>>(ebuf, bbase, row_ptr, csr_src);

    // ---- layer 1 ----  (aggbuf free again after bucket_sort)
    gather6<<<blkN, B, 0, stream>>>(row_ptr, csr_src, x, aggbuf);
    mlp_stats<DIN><<<blkN, B, 0, stream>>>(aggbuf, hbuf, w1a, b1a, w1b, b1b, partial);
    reduce_stats<<<1, B, 0, stream>>>(partial, blkN, g1, be1, ss1);

    // ---- layer 2 (fused gather+BN1+MLP): hbuf -> aggbuf ----
    fused_gin32<<<FUSED_BLOCKS, B, 0, stream>>>(row_ptr, csr_src, hbuf, ss1,
                                                w2a, b2a, w2b, b2b, aggbuf, partial);
    reduce_stats<<<1, B, 0, stream>>>(partial, FUSED_BLOCKS, g2, be2, ss2);

    // ---- layer 3 (fused): aggbuf -> hbuf ----
    fused_gin32<<<FUSED_BLOCKS, B, 0, stream>>>(row_ptr, csr_src, aggbuf, ss2,
                                                w3a, b3a, w3b, b3b, hbuf, partial);
    reduce_stats<<<1, B, 0, stream>>>(partial, FUSED_BLOCKS, g3, be3, ss3);

    // ---- pool (BN3 applied inline) + head ----
    pool2_aff<<<NG, 64, 0, stream>>>(hbuf, gptr, ss3, emb);
    head_kernel<<<(NG + B - 1) / B, B, 0, stream>>>(emb, wb, bb, wm, bm, out);
}

// Round 6
// 385.690 us; speedup vs baseline: 2.5092x; 2.5092x over previous
//
#include <hip/hip_runtime.h>
#include <math.h>

// Problem constants (match reference)
#define NN 150000
#define NE 2400000
#define NG 1024
#define DIN 6
#define DH 32
#define DB 16
#define BN_EPS 1e-5f

#define MLP_BLOCKS ((NN + 255) / 256)   // 586  (layer-1 mlp)
#define FUSED_BLOCKS ((NN + 31) / 32)   // 4688 (fused layers 2/3)
#define RED_BLKS 64                     // stage-1 reduction blocks

// bucket sort params
#define NB 512            // buckets
#define NPB 293           // nodes per bucket (512*293 = 150016 >= NN)
#define SCH 4096          // edges per scatter block
#define EPB 16            // edges per thread in scatter
#define CAP 8192          // max edges per bucket (expected ~4690)
#define NSCAT ((NE + SCH - 1) / SCH)  // 586

// inclusive Hillis-Steele scan of 512 ints in LDS with 256 threads
#define SCAN512(scarr, t)                                     \
    for (int off = 1; off < 512; off <<= 1) {                 \
        int v0 = (t >= off) ? scarr[t - off] : 0;             \
        int v1 = scarr[t + 256 - off];                        \
        __syncthreads();                                      \
        if (t >= off) scarr[t] += v0;                         \
        scarr[t + 256] += v1;                                 \
        __syncthreads();                                      \
    }

// ================= bucket CSR build =================
__global__ void bucket_count(const int* __restrict__ ei, int* __restrict__ bcnt) {
    __shared__ int hist[NB];
    int t = threadIdx.x;
    for (int i = t; i < NB; i += 256) hist[i] = 0;
    __syncthreads();
    long e0 = (long)blockIdx.x * SCH;
#pragma unroll
    for (int k = 0; k < EPB; ++k) {
        long idx = e0 + k * 256 + t;
        if (idx < NE) atomicAdd(&hist[ei[NE + idx] / NPB], 1);
    }
    __syncthreads();
    for (int i = t; i < NB; i += 256)
        if (hist[i]) atomicAdd(&bcnt[i], hist[i]);
}

__global__ void bucket_scan(const int* __restrict__ bcnt,
                            int* __restrict__ bbase, int* __restrict__ bcur) {
    __shared__ int sc[NB];
    int t = threadIdx.x;
    int c0 = bcnt[t], c1 = bcnt[t + 256];
    sc[t] = c0; sc[t + 256] = c1;
    __syncthreads();
    SCAN512(sc, t);
    int e0 = sc[t] - c0, e1 = sc[t + 256] - c1;
    bbase[t] = e0; bbase[t + 256] = e1;
    bcur[t] = e0;  bcur[t + 256] = e1;
    if (t == 0) bbase[NB] = NE;
}

// block-local binning -> semi-coalesced (src,dst) writes into bucket regions
__global__ void bucket_scatter(const int* __restrict__ ei, int* __restrict__ bcur,
                               uint2* __restrict__ ebuf) {
    __shared__ int hist[NB];
    __shared__ int sc[NB];
    __shared__ int lcur[NB];
    __shared__ int gbase[NB];
    __shared__ uint2 stage[SCH];
    int t = threadIdx.x;
    long e0 = (long)blockIdx.x * SCH;
    int s16[EPB], d16[EPB];
    for (int i = t; i < NB; i += 256) hist[i] = 0;
    __syncthreads();
#pragma unroll
    for (int k = 0; k < EPB; ++k) {
        long idx = e0 + k * 256 + t;
        if (idx < NE) {
            s16[k] = ei[idx];
            d16[k] = ei[NE + idx];
            atomicAdd(&hist[d16[k] / NPB], 1);
        } else d16[k] = -1;
    }
    __syncthreads();
    for (int i = t; i < NB; i += 256) sc[i] = hist[i];
    __syncthreads();
    SCAN512(sc, t);
    for (int i = t; i < NB; i += 256) lcur[i] = sc[i] - hist[i];
    __syncthreads();
#pragma unroll
    for (int k = 0; k < EPB; ++k) {
        if (d16[k] >= 0) {
            int b = d16[k] / NPB;
            int p = atomicAdd(&lcur[b], 1);
            stage[p] = make_uint2((unsigned)s16[k], (unsigned)d16[k]);
        }
    }
    __syncthreads();
    for (int i = t; i < NB; i += 256) {
        int h = hist[i];
        gbase[i] = h ? atomicAdd(&bcur[i], h) : 0;
    }
    __syncthreads();
    int cnt = (int)((NE - e0) < SCH ? (NE - e0) : SCH);
    for (int i = t; i < cnt; i += 256) {
        uint2 ed = stage[i];
        int b = (int)ed.y / NPB;
        ebuf[gbase[b] + (i - (sc[b] - hist[b]))] = ed;
    }
}

// per-bucket LDS counting sort -> csr_src + row_ptr (fully coalesced global I/O)
__global__ void bucket_sort(const uint2* __restrict__ ebuf, const int* __restrict__ bbase,
                            int* __restrict__ row_ptr, int* __restrict__ csr_src) {
    __shared__ int deg[NB];
    __shared__ int sc[NB];
    __shared__ int cur[NB];
    __shared__ int srcbuf[CAP];
    int b = blockIdx.x, t = threadIdx.x;
    int node0 = b * NPB;
    int nlocal = (NN - node0) < NPB ? (NN - node0) : NPB;
    int ebase = bbase[b];
    int ecnt = bbase[b + 1] - ebase;
    if (ecnt > CAP) ecnt = CAP;
    for (int i = t; i < NB; i += 256) deg[i] = 0;
    __syncthreads();
    for (int i = t; i < ecnt; i += 256) {
        int d = (int)ebuf[ebase + i].y - node0;
        atomicAdd(&deg[d], 1);
    }
    __syncthreads();
    for (int i = t; i < NB; i += 256) sc[i] = deg[i];
    __syncthreads();
    SCAN512(sc, t);
    for (int j = t; j < nlocal; j += 256) {
        int st = sc[j] - deg[j];
        row_ptr[node0 + j] = ebase + st;
        cur[j] = st;
    }
    if (b == NB - 1 && t == 0) row_ptr[NN] = NE;
    __syncthreads();
    for (int i = t; i < ecnt; i += 256) {
        uint2 ed = ebuf[ebase + i];
        int d = (int)ed.y - node0;
        int p = atomicAdd(&cur[d], 1);
        srcbuf[p] = (int)ed.x;
    }
    __syncthreads();
    for (int i = t; i < ecnt; i += 256) csr_src[ebase + i] = srcbuf[i];
}

// ======= graph boundaries via binary search (batch is sorted) =======
__global__ void gbounds(const int* __restrict__ bat, int* __restrict__ gptr) {
    int g = blockIdx.x * blockDim.x + threadIdx.x;
    if (g > NG) return;
    int lo = 0, hi = NN;
    while (lo < hi) {
        int mid = (lo + hi) >> 1;
        if (bat[mid] < g) lo = mid + 1; else hi = mid;
    }
    gptr[g] = lo;
}

// ================= layer 1: gather (6ch) =================
__global__ void gather6(const int* __restrict__ row_ptr, const int* __restrict__ csr_src,
                        const float* __restrict__ x, float* __restrict__ agg) {
    int node = blockIdx.x * blockDim.x + threadIdx.x;
    if (node >= NN) return;
    int beg = row_ptr[node], end = row_ptr[node + 1];
    const float2* xs = (const float2*)(x + (long)node * DIN);
    float2 a0 = xs[0], a1 = xs[1], a2 = xs[2];   // self term
    for (int e = beg; e < end; ++e) {
        int s = csr_src[e];
        const float2* p = (const float2*)(x + (long)s * DIN);
        float2 b0 = p[0], b1 = p[1], b2 = p[2];
        a0.x += b0.x; a0.y += b0.y;
        a1.x += b1.x; a1.y += b1.y;
        a2.x += b2.x; a2.y += b2.y;
    }
    float2* o = (float2*)(agg + (long)node * DIN);
    o[0] = a0; o[1] = a1; o[2] = a2;
}

// ======== layer 1 MLP + relu + BN-stat partials ========
template <int IN>
__global__ void mlp_stats(const float* __restrict__ agg,
                          float* __restrict__ out,
                          const float* __restrict__ w1, const float* __restrict__ b1,
                          const float* __restrict__ w2, const float* __restrict__ b2,
                          float* __restrict__ partial /* [gridDim][64] */) {
    __shared__ float sw1[IN * DH];
    __shared__ float sw2[DH * DH];
    __shared__ float sb1[DH];
    __shared__ float sb2[DH];
    __shared__ float bsum[DH];
    __shared__ float bsq[DH];
    int t = threadIdx.x;
    for (int i = t; i < IN * DH; i += blockDim.x) sw1[i] = w1[i];
    for (int i = t; i < DH * DH; i += blockDim.x) sw2[i] = w2[i];
    if (t < DH) { sb1[t] = b1[t]; sb2[t] = b2[t]; bsum[t] = 0.f; bsq[t] = 0.f; }
    __syncthreads();

    int node = blockIdx.x * blockDim.x + t;
    bool valid = node < NN;

    float a[IN];
    if (valid) {
        const float* ar = agg + (long)node * IN;
#pragma unroll
        for (int k = 0; k < IN; ++k) a[k] = ar[k];
    } else {
#pragma unroll
        for (int k = 0; k < IN; ++k) a[k] = 0.f;
    }

    float u[DH];
#pragma unroll
    for (int j = 0; j < DH; ++j) {
        float acc = sb1[j];
#pragma unroll
        for (int k = 0; k < IN; ++k) acc += a[k] * sw1[k * DH + j];
        u[j] = fmaxf(acc, 0.f);
    }

    float r[DH];
#pragma unroll
    for (int j = 0; j < DH; ++j) {
        float acc = sb2[j];
#pragma unroll
        for (int k = 0; k < DH; ++k) acc += u[k] * sw2[k * DH + j];
        r[j] = valid ? fmaxf(acc, 0.f) : 0.f;
    }

    if (valid) {
        float4* o = (float4*)(out + (long)node * DH);
#pragma unroll
        for (int q = 0; q < DH / 4; ++q)
            o[q] = make_float4(r[4 * q], r[4 * q + 1], r[4 * q + 2], r[4 * q + 3]);
    }

    int lane = t & 63;
#pragma unroll
    for (int j = 0; j < DH; ++j) {
        float s = r[j];
        float q = r[j] * r[j];
        for (int o = 32; o > 0; o >>= 1) {
            s += __shfl_xor(s, o);
            q += __shfl_xor(q, o);
        }
        if (lane == 0) {
            atomicAdd(&bsum[j], s);   // LDS atomic, cheap
            atomicAdd(&bsq[j], q);
        }
    }
    __syncthreads();
    if (t < 2 * DH) {
        float v = (t < DH) ? bsum[t] : bsq[t - DH];
        partial[(long)blockIdx.x * (2 * DH) + t] = v;
    }
}

// ======== fused layers 2/3: gather(BN-affine folded) + MLP + stats ========
// 32 nodes / block, 8 threads / node. h (input) and out MUST be different buffers.
__global__ void __launch_bounds__(256) fused_gin32(
    const int* __restrict__ row_ptr, const int* __restrict__ csr_src,
    const float* __restrict__ h, const float* __restrict__ ss,
    const float* __restrict__ w1, const float* __restrict__ b1,
    const float* __restrict__ w2, const float* __restrict__ b2,
    float* __restrict__ out, float* __restrict__ partial /* [gridDim][64] */) {
    __shared__ float sw1[DH * DH];
    __shared__ float sw2[DH * DH];
    __shared__ float sb1[DH];
    __shared__ float sb2[DH];
    __shared__ float sagg[32][DH + 1];
    __shared__ float su[32][DH + 1];
    __shared__ float bsum[DH];
    __shared__ float bsq[DH];
    int t = threadIdx.x;
    for (int i = t; i < DH * DH; i += 256) { sw1[i] = w1[i]; sw2[i] = w2[i]; }
    if (t < DH) { sb1[t] = b1[t]; sb2[t] = b2[t]; bsum[t] = 0.f; bsq[t] = 0.f; }

    int nl = t >> 3, sub = t & 7;
    int node = blockIdx.x * 32 + nl;
    bool valid = node < NN;

    // ---- gather (8 threads/node, float4 each) + affine fold ----
    float4 acc = make_float4(0.f, 0.f, 0.f, 0.f);
    int beg = 0, end = 0;
    if (valid) {
        beg = row_ptr[node];
        end = row_ptr[node + 1];
        acc = *((const float4*)(h + (long)node * DH) + sub);
    }
    for (int e = beg; e < end; ++e) {
        int s = csr_src[e];
        float4 v = *((const float4*)(h + (long)s * DH) + sub);
        acc.x += v.x; acc.y += v.y; acc.z += v.z; acc.w += v.w;
    }
    float cnt = (float)(end - beg + 1);
    float4 scv = ((const float4*)ss)[sub];
    float4 shv = ((const float4*)(ss + DH))[sub];
    sagg[nl][sub * 4 + 0] = acc.x * scv.x + cnt * shv.x;
    sagg[nl][sub * 4 + 1] = acc.y * scv.y + cnt * shv.y;
    sagg[nl][sub * 4 + 2] = acc.z * scv.z + cnt * shv.z;
    sagg[nl][sub * 4 + 3] = acc.w * scv.w + cnt * shv.w;
    __syncthreads();

    // ---- MLP layer A: each thread computes 4 of 32 outputs ----
#pragma unroll
    for (int i = 0; i < 4; ++i) {
        int j = sub * 4 + i;
        float a = sb1[j];
#pragma unroll
        for (int k = 0; k < DH; ++k) a += sagg[nl][k] * sw1[k * DH + j];
        su[nl][j] = fmaxf(a, 0.f);
    }
    __syncthreads();

    // ---- MLP layer B + relu ----
    float r[4];
#pragma unroll
    for (int i = 0; i < 4; ++i) {
        int j = sub * 4 + i;
        float a = sb2[j];
#pragma unroll
        for (int k = 0; k < DH; ++k) a += su[nl][k] * sw2[k * DH + j];
        r[i] = valid ? fmaxf(a, 0.f) : 0.f;
    }
    if (valid)
        *((float4*)(out + (long)node * DH) + sub) = make_float4(r[0], r[1], r[2], r[3]);

    // ---- stats: butterfly over the 8 nodes in this wave, then LDS atomic ----
    float s0 = r[0], s1 = r[1], s2 = r[2], s3 = r[3];
    float q0 = r[0] * r[0], q1 = r[1] * r[1], q2 = r[2] * r[2], q3 = r[3] * r[3];
#pragma unroll
    for (int o = 8; o < 64; o <<= 1) {
        s0 += __shfl_xor(s0, o); s1 += __shfl_xor(s1, o);
        s2 += __shfl_xor(s2, o); s3 += __shfl_xor(s3, o);
        q0 += __shfl_xor(q0, o); q1 += __shfl_xor(q1, o);
        q2 += __shfl_xor(q2, o); q3 += __shfl_xor(q3, o);
    }
    if ((t & 63) < 8) {
        int j = sub * 4;
        atomicAdd(&bsum[j + 0], s0); atomicAdd(&bsum[j + 1], s1);
        atomicAdd(&bsum[j + 2], s2); atomicAdd(&bsum[j + 3], s3);
        atomicAdd(&bsq[j + 0], q0);  atomicAdd(&bsq[j + 1], q1);
        atomicAdd(&bsq[j + 2], q2);  atomicAdd(&bsq[j + 3], q3);
    }
    __syncthreads();
    if (t < 2 * DH) {
        float v = (t < DH) ? bsum[t] : bsq[t - DH];
        partial[(long)blockIdx.x * (2 * DH) + t] = v;
    }
}

// ===== stage 1: fold partial[nblk][64] -> partial2[RED_BLKS][64], coalesced =====
__global__ void reduce_partial(const float* __restrict__ partial, int nblk,
                               float* __restrict__ partial2) {
    __shared__ float sred[4][64];
    int t = threadIdx.x;           // 256
    int ch = t & 63, sub = t >> 6;
    int chunk = (nblk + RED_BLKS - 1) / RED_BLKS;
    int start = blockIdx.x * chunk;
    int end = start + chunk; if (end > nblk) end = nblk;
    float acc = 0.f;
    for (int r = start + sub; r < end; r += 4)
        acc += partial[(long)r * 64 + ch];
    sred[sub][ch] = acc;
    __syncthreads();
    if (t < 64)
        partial2[(long)blockIdx.x * 64 + t] =
            sred[0][t] + sred[1][t] + sred[2][t] + sred[3][t];
}

// ===== stage 2: fold partial2 + finalize BN scale/shift =====
__global__ void finalize_stats(const float* __restrict__ partial2,
                               const float* __restrict__ g, const float* __restrict__ be,
                               float* __restrict__ ss) {
    __shared__ float sred[4][64];
    __shared__ float sums[64];
    int t = threadIdx.x;           // 256
    int ch = t & 63, sub = t >> 6;
    float acc = 0.f;
    for (int r = sub; r < RED_BLKS; r += 4) acc += partial2[(long)r * 64 + ch];
    sred[sub][ch] = acc;
    __syncthreads();
    if (t < 64) sums[t] = sred[0][t] + sred[1][t] + sred[2][t] + sred[3][t];
    __syncthreads();
    if (t < DH) {
        float mu = sums[t] * (1.0f / NN);
        float var = sums[DH + t] * (1.0f / NN) - mu * mu;
        float sc = g[t] * rsqrtf(var + BN_EPS);
        ss[t] = sc;
        ss[DH + t] = be[t] - mu * sc;
    }
}

// ====== per-graph mean pool of BN(h), affine folded: sc*mean(h)+sh ======
__global__ void pool2_aff(const float* __restrict__ h, const int* __restrict__ gptr,
                          const float* __restrict__ ss, float* __restrict__ emb) {
    int g = blockIdx.x;
    int t = threadIdx.x;           // 64 threads
    int beg = gptr[g], end = gptr[g + 1];
    int d = t & 31, half = t >> 5;
    float acc = 0.f;
    for (int n = beg + half; n < end; n += 2) acc += h[(long)n * DH + d];
    acc += __shfl_xor(acc, 32);
    if (t < 32) {
        int c = end - beg;
        float val = 0.f;
        if (c > 0) val = ss[d] * (acc / (float)c) + ss[DH + d];
        emb[(long)g * DH + d] = val;
    }
}

// ================= head: emb -> 16 relu -> 1 sigmoid =================
__global__ void head_kernel(const float* __restrict__ emb,
                            const float* __restrict__ wb, const float* __restrict__ bb,
                            const float* __restrict__ wm, const float* __restrict__ bm,
                            float* __restrict__ out) {
    __shared__ float swb[DH * DB];
    __shared__ float sbb[DB];
    __shared__ float swm[DB];
    int t = threadIdx.x;
    for (int i = t; i < DH * DB; i += blockDim.x) swb[i] = wb[i];
    if (t < DB) { sbb[t] = bb[t]; swm[t] = wm[t]; }
    __syncthreads();

    int g = blockIdx.x * blockDim.x + t;
    if (g >= NG) return;
    float e[DH];
#pragma unroll
    for (int d = 0; d < DH; ++d) e[d] = emb[(long)g * DH + d];
    float acc = bm[0];
#pragma unroll
    for (int j = 0; j < DB; ++j) {
        float z = sbb[j];
#pragma unroll
        for (int d = 0; d < DH; ++d) z += e[d] * swb[d * DB + j];
        z = fmaxf(z, 0.f);
        acc += z * swm[j];
    }
    out[g] = 1.0f / (1.0f + expf(-acc));
}

extern "C" void kernel_launch(void* const* d_in, const int* in_sizes, int n_in,
                              void* d_out, int out_size, void* d_ws, size_t ws_size,
                              hipStream_t stream) {
    const float* x   = (const float*)d_in[0];
    const int*   ei  = (const int*)d_in[1];
    const int*   bat = (const int*)d_in[2];
    const float* w1a = (const float*)d_in[3];  const float* b1a = (const float*)d_in[4];
    const float* w1b = (const float*)d_in[5];  const float* b1b = (const float*)d_in[6];
    const float* g1  = (const float*)d_in[7];  const float* be1 = (const float*)d_in[8];
    const float* w2a = (const float*)d_in[9];  const float* b2a = (const float*)d_in[10];
    const float* w2b = (const float*)d_in[11]; const float* b2b = (const float*)d_in[12];
    const float* g2  = (const float*)d_in[13]; const float* be2 = (const float*)d_in[14];
    const float* w3a = (const float*)d_in[15]; const float* b3a = (const float*)d_in[16];
    const float* w3b = (const float*)d_in[17]; const float* b3b = (const float*)d_in[18];
    const float* g3  = (const float*)d_in[19]; const float* be3 = (const float*)d_in[20];
    const float* wb  = (const float*)d_in[21]; const float* bb  = (const float*)d_in[22];
    const float* wm  = (const float*)d_in[23]; const float* bm  = (const float*)d_in[24];
    float* out = (float*)d_out;

    // ---- workspace layout (4-byte units) ----
    char* wsb = (char*)d_ws;
    float* hbuf    = (float*)wsb;                               // NN*DH
    float* aggbuf  = hbuf + (long)NN * DH;                      // NN*DH (aliased: ebuf during CSR build; layer-1 agg; ping-pong)
    uint2* ebuf    = (uint2*)aggbuf;
    int*   csr_src = (int*)(aggbuf + (long)NN * DH);            // NE
    int*   row_ptr = csr_src + NE;                              // NN+1
    int*   bbase   = row_ptr + NN + 1;                          // NB+1
    int*   bcur    = bbase + NB + 1;                            // NB
    int*   gptr    = bcur + NB;                                 // NG+1
    float* emb     = (float*)(gptr + NG + 1);                   // NG*DH
    float* ss1     = emb + (long)NG * DH;                       // 64 (BN scale/shift)
    float* ss2     = ss1 + 2 * DH;                              // 64
    float* ss3     = ss2 + 2 * DH;                              // 64
    float* partial2= ss3 + 2 * DH;                              // RED_BLKS*64
    float* partial = partial2 + (long)RED_BLKS * 64;            // FUSED_BLOCKS*64
    int*   bcnt    = (int*)(partial + (long)FUSED_BLOCKS * 2 * DH); // NB (zeroed)

    hipMemsetAsync(bcnt, 0, (size_t)NB * 4, stream);

    const int B = 256;
    int blkN = (NN + B - 1) / B;        // == MLP_BLOCKS

    // ---- CSR via two-level bucket sort (all random access in LDS) ----
    bucket_count<<<NSCAT, B, 0, stream>>>(ei, bcnt);
    gbounds<<<(NG + 1 + B - 1) / B, B, 0, stream>>>(bat, gptr);
    bucket_scan<<<1, B, 0, stream>>>(bcnt, bbase, bcur);
    bucket_scatter<<<NSCAT, B, 0, stream>>>(ei, bcur, ebuf);
    bucket_sort<<<NB, B, 0, stream>>>(ebuf, bbase, row_ptr, csr_src);

    // ---- layer 1 ----  (aggbuf free again after bucket_sort)
    gather6<<<blkN, B, 0, stream>>>(row_ptr, csr_src, x, aggbuf);
    mlp_stats<DIN><<<blkN, B, 0, stream>>>(aggbuf, hbuf, w1a, b1a, w1b, b1b, partial);
    reduce_partial<<<RED_BLKS, B, 0, stream>>>(partial, blkN, partial2);
    finalize_stats<<<1, B, 0, stream>>>(partial2, g1, be1, ss1);

    // ---- layer 2 (fused gather+BN1+MLP): hbuf -> aggbuf ----
    fused_gin32<<<FUSED_BLOCKS, B, 0, stream>>>(row_ptr, csr_src, hbuf, ss1,
                                                w2a, b2a, w2b, b2b, aggbuf, partial);
    reduce_partial<<<RED_BLKS, B, 0, stream>>>(partial, FUSED_BLOCKS, partial2);
    finalize_stats<<<1, B, 0, stream>>>(partial2, g2, be2, ss2);

    // ---- layer 3 (fused): aggbuf -> hbuf ----
    fused_gin32<<<FUSED_BLOCKS, B, 0, stream>>>(row_ptr, csr_src, aggbuf, ss2,
                                                w3a, b3a, w3b, b3b, hbuf, partial);
    reduce_partial<<<RED_BLKS, B, 0, stream>>>(partial, FUSED_BLOCKS, partial2);
    finalize_stats<<<1, B, 0, stream>>>(partial2, g3, be3, ss3);

    // ---- pool (BN3 applied inline) + head ----
    pool2_aff<<<NG, 64, 0, stream>>>(hbuf, gptr, ss3, emb);
    head_kernel<<<(NG + B - 1) / B, B, 0, stream>>>(emb, wb, bb, wm, bm, out);
}

// Round 7
// 365.070 us; speedup vs baseline: 2.6510x; 1.0565x over previous
//
#include <hip/hip_runtime.h>
#include <hip/hip_fp16.h>
#include <math.h>

// Problem constants (match reference)
#define NN 150000
#define NE 2400000
#define NG 1024
#define DIN 6
#define DH 32
#define DB 16
#define BN_EPS 1e-5f

#define MLP_BLOCKS ((NN + 255) / 256)   // 586  (layer-1 mlp)
#define FUSED_BLOCKS ((NN + 63) / 64)   // 2344 (fused layers 2/3, 64 nodes/block)
#define RED_BLKS 64                     // stage-1 reduction blocks

// bucket sort params
#define NB 512            // buckets
#define NPB 293           // nodes per bucket (512*293 = 150016 >= NN); NPB < 512 so 9 bits
#define SCH 4096          // edges per scatter block
#define EPB 16            // edges per thread in scatter
#define CAP 8192          // max edges per bucket (expected ~4690)
#define NSCAT ((NE + SCH - 1) / SCH)  // 586

// inclusive Hillis-Steele scan of 512 ints in LDS with 256 threads
#define SCAN512(scarr, t)                                     \
    for (int off = 1; off < 512; off <<= 1) {                 \
        int v0 = (t >= off) ? scarr[t - off] : 0;             \
        int v1 = scarr[t + 256 - off];                        \
        __syncthreads();                                      \
        if (t >= off) scarr[t] += v0;                         \
        scarr[t + 256] += v1;                                 \
        __syncthreads();                                      \
    }

__device__ inline void addh8(float* a, uint4 v) {
    const __half2* hp = (const __half2*)&v;
#pragma unroll
    for (int i = 0; i < 4; ++i) {
        float2 f = __half22float2(hp[i]);
        a[2 * i] += f.x; a[2 * i + 1] += f.y;
    }
}

// ================= bucket CSR build =================
__global__ void bucket_count(const int* __restrict__ ei, int* __restrict__ bcnt) {
    __shared__ int hist[NB];
    int t = threadIdx.x;
    for (int i = t; i < NB; i += 256) hist[i] = 0;
    __syncthreads();
    long e0 = (long)blockIdx.x * SCH;
#pragma unroll
    for (int k = 0; k < EPB; ++k) {
        long idx = e0 + k * 256 + t;
        if (idx < NE) atomicAdd(&hist[ei[NE + idx] / NPB], 1);
    }
    __syncthreads();
    for (int i = t; i < NB; i += 256)
        if (hist[i]) atomicAdd(&bcnt[i], hist[i]);
}

__global__ void bucket_scan(const int* __restrict__ bcnt,
                            int* __restrict__ bbase, int* __restrict__ bcur) {
    __shared__ int sc[NB];
    int t = threadIdx.x;
    int c0 = bcnt[t], c1 = bcnt[t + 256];
    sc[t] = c0; sc[t + 256] = c1;
    __syncthreads();
    SCAN512(sc, t);
    int e0 = sc[t] - c0, e1 = sc[t + 256] - c1;
    bbase[t] = e0; bbase[t + 256] = e1;
    bcur[t] = e0;  bcur[t + 256] = e1;
    if (t == 0) bbase[NB] = NE;
}

// block-local binning -> packed (src<<9|dst_local) writes into bucket regions
__global__ void bucket_scatter(const int* __restrict__ ei, int* __restrict__ bcur,
                               unsigned* __restrict__ ebuf) {
    __shared__ int hist[NB];
    __shared__ int sc[NB];
    __shared__ int lcur[NB];
    __shared__ int gbase[NB];
    __shared__ unsigned stage[SCH];
    __shared__ unsigned short stageb[SCH];
    int t = threadIdx.x;
    long e0 = (long)blockIdx.x * SCH;
    int s16[EPB], d16[EPB];
    for (int i = t; i < NB; i += 256) hist[i] = 0;
    __syncthreads();
#pragma unroll
    for (int k = 0; k < EPB; ++k) {
        long idx = e0 + k * 256 + t;
        if (idx < NE) {
            s16[k] = ei[idx];
            d16[k] = ei[NE + idx];
            atomicAdd(&hist[d16[k] / NPB], 1);
        } else d16[k] = -1;
    }
    __syncthreads();
    for (int i = t; i < NB; i += 256) sc[i] = hist[i];
    __syncthreads();
    SCAN512(sc, t);
    for (int i = t; i < NB; i += 256) lcur[i] = sc[i] - hist[i];
    __syncthreads();
#pragma unroll
    for (int k = 0; k < EPB; ++k) {
        if (d16[k] >= 0) {
            int b = d16[k] / NPB;
            int p = atomicAdd(&lcur[b], 1);
            stage[p] = ((unsigned)s16[k] << 9) | (unsigned)(d16[k] - b * NPB);
            stageb[p] = (unsigned short)b;
        }
    }
    __syncthreads();
    for (int i = t; i < NB; i += 256) {
        int h = hist[i];
        gbase[i] = h ? atomicAdd(&bcur[i], h) : 0;
    }
    __syncthreads();
    int cnt = (int)((NE - e0) < SCH ? (NE - e0) : SCH);
    for (int i = t; i < cnt; i += 256) {
        int b = stageb[i];
        ebuf[gbase[b] + (i - (sc[b] - hist[b]))] = stage[i];
    }
}

// per-bucket LDS counting sort -> csr_src + row_ptr (fully coalesced global I/O)
__global__ void bucket_sort(const unsigned* __restrict__ ebuf, const int* __restrict__ bbase,
                            int* __restrict__ row_ptr, int* __restrict__ csr_src) {
    __shared__ int deg[NB];
    __shared__ int sc[NB];
    __shared__ int cur[NB];
    __shared__ int srcbuf[CAP];
    int b = blockIdx.x, t = threadIdx.x;
    int node0 = b * NPB;
    int nlocal = (NN - node0) < NPB ? (NN - node0) : NPB;
    int ebase = bbase[b];
    int ecnt = bbase[b + 1] - ebase;
    if (ecnt > CAP) ecnt = CAP;
    for (int i = t; i < NB; i += 256) deg[i] = 0;
    __syncthreads();
    for (int i = t; i < ecnt; i += 256) {
        atomicAdd(&deg[ebuf[ebase + i] & 511u], 1);
    }
    __syncthreads();
    for (int i = t; i < NB; i += 256) sc[i] = deg[i];
    __syncthreads();
    SCAN512(sc, t);
    for (int j = t; j < nlocal; j += 256) {
        int st = sc[j] - deg[j];
        row_ptr[node0 + j] = ebase + st;
        cur[j] = st;
    }
    if (b == NB - 1 && t == 0) row_ptr[NN] = NE;
    __syncthreads();
    for (int i = t; i < ecnt; i += 256) {
        unsigned v = ebuf[ebase + i];
        int p = atomicAdd(&cur[v & 511u], 1);
        srcbuf[p] = (int)(v >> 9);
    }
    __syncthreads();
    for (int i = t; i < ecnt; i += 256) csr_src[ebase + i] = srcbuf[i];
}

// ======= graph boundaries via binary search (batch is sorted) =======
__global__ void gbounds(const int* __restrict__ bat, int* __restrict__ gptr) {
    int g = blockIdx.x * blockDim.x + threadIdx.x;
    if (g > NG) return;
    int lo = 0, hi = NN;
    while (lo < hi) {
        int mid = (lo + hi) >> 1;
        if (bat[mid] < g) lo = mid + 1; else hi = mid;
    }
    gptr[g] = lo;
}

// ================= layer 1: gather (6ch, fp32 input x) =================
__global__ void gather6(const int* __restrict__ row_ptr, const int* __restrict__ csr_src,
                        const float* __restrict__ x, float* __restrict__ agg) {
    int node = blockIdx.x * blockDim.x + threadIdx.x;
    if (node >= NN) return;
    int beg = row_ptr[node], end = row_ptr[node + 1];
    const float2* xs = (const float2*)(x + (long)node * DIN);
    float2 a0 = xs[0], a1 = xs[1], a2 = xs[2];   // self term
    for (int e = beg; e < end; ++e) {
        int s = csr_src[e];
        const float2* p = (const float2*)(x + (long)s * DIN);
        float2 b0 = p[0], b1 = p[1], b2 = p[2];
        a0.x += b0.x; a0.y += b0.y;
        a1.x += b1.x; a1.y += b1.y;
        a2.x += b2.x; a2.y += b2.y;
    }
    float2* o = (float2*)(agg + (long)node * DIN);
    o[0] = a0; o[1] = a1; o[2] = a2;
}

// ======== layer 1 MLP + relu + BN-stat partials; fp16 output ========
template <int IN>
__global__ void mlp_stats(const float* __restrict__ agg,
                          __half* __restrict__ out,
                          const float* __restrict__ w1, const float* __restrict__ b1,
                          const float* __restrict__ w2, const float* __restrict__ b2,
                          float* __restrict__ partial /* [gridDim][64] */) {
    __shared__ float sw1[IN * DH];
    __shared__ float sw2[DH * DH];
    __shared__ float sb1[DH];
    __shared__ float sb2[DH];
    __shared__ float bsum[DH];
    __shared__ float bsq[DH];
    int t = threadIdx.x;
    for (int i = t; i < IN * DH; i += blockDim.x) sw1[i] = w1[i];
    for (int i = t; i < DH * DH; i += blockDim.x) sw2[i] = w2[i];
    if (t < DH) { sb1[t] = b1[t]; sb2[t] = b2[t]; bsum[t] = 0.f; bsq[t] = 0.f; }
    __syncthreads();

    int node = blockIdx.x * blockDim.x + t;
    bool valid = node < NN;

    float a[IN];
    if (valid) {
        const float* ar = agg + (long)node * IN;
#pragma unroll
        for (int k = 0; k < IN; ++k) a[k] = ar[k];
    } else {
#pragma unroll
        for (int k = 0; k < IN; ++k) a[k] = 0.f;
    }

    float u[DH];
#pragma unroll
    for (int j = 0; j < DH; ++j) {
        float acc = sb1[j];
#pragma unroll
        for (int k = 0; k < IN; ++k) acc += a[k] * sw1[k * DH + j];
        u[j] = fmaxf(acc, 0.f);
    }

    float r[DH];
#pragma unroll
    for (int j = 0; j < DH; ++j) {
        float acc = sb2[j];
#pragma unroll
        for (int k = 0; k < DH; ++k) acc += u[k] * sw2[k * DH + j];
        r[j] = valid ? fmaxf(acc, 0.f) : 0.f;
    }

    if (valid) {
        uint4* o = (uint4*)(out + (long)node * DH);
#pragma unroll
        for (int q = 0; q < 4; ++q) {
            uint4 v;
            unsigned* vp = (unsigned*)&v;
#pragma unroll
            for (int i = 0; i < 4; ++i) {
                __half2 hh = __floats2half2_rn(r[q * 8 + 2 * i], r[q * 8 + 2 * i + 1]);
                vp[i] = *(unsigned*)&hh;
            }
            o[q] = v;
        }
    }

    int lane = t & 63;
#pragma unroll
    for (int j = 0; j < DH; ++j) {
        float s = r[j];
        float q = r[j] * r[j];
        for (int o = 32; o > 0; o >>= 1) {
            s += __shfl_xor(s, o);
            q += __shfl_xor(q, o);
        }
        if (lane == 0) {
            atomicAdd(&bsum[j], s);   // LDS atomic, cheap
            atomicAdd(&bsq[j], q);
        }
    }
    __syncthreads();
    if (t < 2 * DH) {
        float v = (t < DH) ? bsum[t] : bsq[t - DH];
        partial[(long)blockIdx.x * (2 * DH) + t] = v;
    }
}

// ======== fused layers 2/3 (fp16 h): gather(BN folded) + MLP + stats ========
// 64 nodes / block, 4 threads / node (8 channels each). in/out distinct buffers.
__global__ void __launch_bounds__(256) fused_gin16(
    const int* __restrict__ row_ptr, const int* __restrict__ csr_src,
    const __half* __restrict__ h, const float* __restrict__ ss,
    const float* __restrict__ w1, const float* __restrict__ b1,
    const float* __restrict__ w2, const float* __restrict__ b2,
    __half* __restrict__ out, float* __restrict__ partial /* [gridDim][64] */) {
    __shared__ float sw1[DH * DH];
    __shared__ float sw2[DH * DH];
    __shared__ float sb1[DH];
    __shared__ float sb2[DH];
    __shared__ float sagg[64][DH + 1];
    __shared__ float su[64][DH + 1];
    __shared__ float bsum[DH];
    __shared__ float bsq[DH];
    int t = threadIdx.x;
    for (int i = t; i < DH * DH; i += 256) { sw1[i] = w1[i]; sw2[i] = w2[i]; }
    if (t < DH) { sb1[t] = b1[t]; sb2[t] = b2[t]; bsum[t] = 0.f; bsq[t] = 0.f; }

    int nl = t >> 2, sub = t & 3;
    int node = blockIdx.x * 64 + nl;
    bool valid = node < NN;

    // ---- gather (4 threads/node, 8 fp16 ch each = 16B loads) ----
    const uint4* hb = (const uint4*)h;   // node row = 4 uint4
    float a[8] = {0.f, 0.f, 0.f, 0.f, 0.f, 0.f, 0.f, 0.f};
    int beg = 0, end = 0;
    if (valid) {
        beg = row_ptr[node];
        end = row_ptr[node + 1];
        addh8(a, hb[(long)node * 4 + sub]);     // self term
    }
    for (int e = beg; e < end; ++e) {
        int s = csr_src[e];
        addh8(a, hb[(long)s * 4 + sub]);
    }
    float cnt = (float)(end - beg + 1);
    int j0 = sub * 8;
#pragma unroll
    for (int i = 0; i < 8; ++i)
        sagg[nl][j0 + i] = a[i] * ss[j0 + i] + cnt * ss[DH + j0 + i];
    __syncthreads();

    // ---- MLP layer A: each thread computes 8 of 32 outputs ----
#pragma unroll
    for (int i = 0; i < 8; ++i) {
        int j = j0 + i;
        float acc = sb1[j];
#pragma unroll
        for (int k = 0; k < DH; ++k) acc += sagg[nl][k] * sw1[k * DH + j];
        su[nl][j] = fmaxf(acc, 0.f);
    }
    __syncthreads();

    // ---- MLP layer B + relu ----
    float r[8];
#pragma unroll
    for (int i = 0; i < 8; ++i) {
        int j = j0 + i;
        float acc = sb2[j];
#pragma unroll
        for (int k = 0; k < DH; ++k) acc += su[nl][k] * sw2[k * DH + j];
        r[i] = valid ? fmaxf(acc, 0.f) : 0.f;
    }
    if (valid) {
        uint4 o;
        unsigned* op = (unsigned*)&o;
#pragma unroll
        for (int i = 0; i < 4; ++i) {
            __half2 hh = __floats2half2_rn(r[2 * i], r[2 * i + 1]);
            op[i] = *(unsigned*)&hh;
        }
        ((uint4*)out)[(long)node * 4 + sub] = o;
    }

    // ---- stats: butterfly over the 16 nodes in this wave, then LDS atomic ----
    float s[8], q[8];
#pragma unroll
    for (int i = 0; i < 8; ++i) { s[i] = r[i]; q[i] = r[i] * r[i]; }
#pragma unroll
    for (int o = 4; o < 64; o <<= 1) {
#pragma unroll
        for (int i = 0; i < 8; ++i) {
            s[i] += __shfl_xor(s[i], o);
            q[i] += __shfl_xor(q[i], o);
        }
    }
    if ((t & 63) < 4) {
#pragma unroll
        for (int i = 0; i < 8; ++i) {
            atomicAdd(&bsum[j0 + i], s[i]);
            atomicAdd(&bsq[j0 + i], q[i]);
        }
    }
    __syncthreads();
    if (t < 2 * DH) {
        float v = (t < DH) ? bsum[t] : bsq[t - DH];
        partial[(long)blockIdx.x * (2 * DH) + t] = v;
    }
}

// ===== stage 1: fold partial[nblk][64] -> partial2[RED_BLKS][64], coalesced =====
__global__ void reduce_partial(const float* __restrict__ partial, int nblk,
                               float* __restrict__ partial2) {
    __shared__ float sred[4][64];
    int t = threadIdx.x;           // 256
    int ch = t & 63, sub = t >> 6;
    int chunk = (nblk + RED_BLKS - 1) / RED_BLKS;
    int start = blockIdx.x * chunk;
    int end = start + chunk; if (end > nblk) end = nblk;
    float acc = 0.f;
    for (int r = start + sub; r < end; r += 4)
        acc += partial[(long)r * 64 + ch];
    sred[sub][ch] = acc;
    __syncthreads();
    if (t < 64)
        partial2[(long)blockIdx.x * 64 + t] =
            sred[0][t] + sred[1][t] + sred[2][t] + sred[3][t];
}

// ===== stage 2: fold partial2 + finalize BN scale/shift =====
__global__ void finalize_stats(const float* __restrict__ partial2,
                               const float* __restrict__ g, const float* __restrict__ be,
                               float* __restrict__ ss) {
    __shared__ float sred[4][64];
    __shared__ float sums[64];
    int t = threadIdx.x;           // 256
    int ch = t & 63, sub = t >> 6;
    float acc = 0.f;
    for (int r = sub; r < RED_BLKS; r += 4) acc += partial2[(long)r * 64 + ch];
    sred[sub][ch] = acc;
    __syncthreads();
    if (t < 64) sums[t] = sred[0][t] + sred[1][t] + sred[2][t] + sred[3][t];
    __syncthreads();
    if (t < DH) {
        float mu = sums[t] * (1.0f / NN);
        float var = sums[DH + t] * (1.0f / NN) - mu * mu;
        float sc = g[t] * rsqrtf(var + BN_EPS);
        ss[t] = sc;
        ss[DH + t] = be[t] - mu * sc;
    }
}

// ====== per-graph mean pool of BN(h), affine folded: sc*mean(h)+sh ======
__global__ void pool2_aff(const __half* __restrict__ h, const int* __restrict__ gptr,
                          const float* __restrict__ ss, float* __restrict__ emb) {
    int g = blockIdx.x;
    int t = threadIdx.x;           // 64 threads
    int beg = gptr[g], end = gptr[g + 1];
    int d = t & 31, half = t >> 5;
    float acc = 0.f;
    for (int n = beg + half; n < end; n += 2) acc += __half2float(h[(long)n * DH + d]);
    acc += __shfl_xor(acc, 32);
    if (t < 32) {
        int c = end - beg;
        float val = 0.f;
        if (c > 0) val = ss[d] * (acc / (float)c) + ss[DH + d];
        emb[(long)g * DH + d] = val;
    }
}

// ================= head: emb -> 16 relu -> 1 sigmoid =================
__global__ void head_kernel(const float* __restrict__ emb,
                            const float* __restrict__ wb, const float* __restrict__ bb,
                            const float* __restrict__ wm, const float* __restrict__ bm,
                            float* __restrict__ out) {
    __shared__ float swb[DH * DB];
    __shared__ float sbb[DB];
    __shared__ float swm[DB];
    int t = threadIdx.x;
    for (int i = t; i < DH * DB; i += blockDim.x) swb[i] = wb[i];
    if (t < DB) { sbb[t] = bb[t]; swm[t] = wm[t]; }
    __syncthreads();

    int g = blockIdx.x * blockDim.x + t;
    if (g >= NG) return;
    float e[DH];
#pragma unroll
    for (int d = 0; d < DH; ++d) e[d] = emb[(long)g * DH + d];
    float acc = bm[0];
#pragma unroll
    for (int j = 0; j < DB; ++j) {
        float z = sbb[j];
#pragma unroll
        for (int d = 0; d < DH; ++d) z += e[d] * swb[d * DB + j];
        z = fmaxf(z, 0.f);
        acc += z * swm[j];
    }
    out[g] = 1.0f / (1.0f + expf(-acc));
}

extern "C" void kernel_launch(void* const* d_in, const int* in_sizes, int n_in,
                              void* d_out, int out_size, void* d_ws, size_t ws_size,
                              hipStream_t stream) {
    const float* x   = (const float*)d_in[0];
    const int*   ei  = (const int*)d_in[1];
    const int*   bat = (const int*)d_in[2];
    const float* w1a = (const float*)d_in[3];  const float* b1a = (const float*)d_in[4];
    const float* w1b = (const float*)d_in[5];  const float* b1b = (const float*)d_in[6];
    const float* g1  = (const float*)d_in[7];  const float* be1 = (const float*)d_in[8];
    const float* w2a = (const float*)d_in[9];  const float* b2a = (const float*)d_in[10];
    const float* w2b = (const float*)d_in[11]; const float* b2b = (const float*)d_in[12];
    const float* g2  = (const float*)d_in[13]; const float* be2 = (const float*)d_in[14];
    const float* w3a = (const float*)d_in[15]; const float* b3a = (const float*)d_in[16];
    const float* w3b = (const float*)d_in[17]; const float* b3b = (const float*)d_in[18];
    const float* g3  = (const float*)d_in[19]; const float* be3 = (const float*)d_in[20];
    const float* wb  = (const float*)d_in[21]; const float* bb  = (const float*)d_in[22];
    const float* wm  = (const float*)d_in[23]; const float* bm  = (const float*)d_in[24];
    float* out = (float*)d_out;

    // ---- workspace layout (4-byte units) ----
    char* wsb = (char*)d_ws;
    float* hbuf    = (float*)wsb;                               // NN*DH fp32 region; used as fp16 h (half the bytes)
    float* aggbuf  = hbuf + (long)NN * DH;                      // NN*DH region (aliased: ebuf uint[NE]; layer-1 fp32 agg; fp16 ping-pong)
    unsigned* ebuf = (unsigned*)aggbuf;
    int*   csr_src = (int*)(aggbuf + (long)NN * DH);            // NE
    int*   row_ptr = csr_src + NE;                              // NN+1
    int*   bbase   = row_ptr + NN + 1;                          // NB+1
    int*   bcur    = bbase + NB + 1;                            // NB
    int*   gptr    = bcur + NB;                                 // NG+1
    float* emb     = (float*)(gptr + NG + 1);                   // NG*DH
    float* ss1     = emb + (long)NG * DH;                       // 64 (BN scale/shift)
    float* ss2     = ss1 + 2 * DH;                              // 64
    float* ss3     = ss2 + 2 * DH;                              // 64
    float* partial2= ss3 + 2 * DH;                              // RED_BLKS*64
    float* partial = partial2 + (long)RED_BLKS * 64;            // FUSED_BLOCKS*64 (>= MLP_BLOCKS)
    int*   bcnt    = (int*)(partial + (long)FUSED_BLOCKS * 2 * DH); // NB (zeroed)

    __half* hbuf16 = (__half*)hbuf;
    __half* abuf16 = (__half*)aggbuf;

    hipMemsetAsync(bcnt, 0, (size_t)NB * 4, stream);

    const int B = 256;
    int blkN = (NN + B - 1) / B;        // == MLP_BLOCKS

    // ---- CSR via two-level bucket sort (all random access in LDS) ----
    bucket_count<<<NSCAT, B, 0, stream>>>(ei, bcnt);
    gbounds<<<(NG + 1 + B - 1) / B, B, 0, stream>>>(bat, gptr);
    bucket_scan<<<1, B, 0, stream>>>(bcnt, bbase, bcur);
    bucket_scatter<<<NSCAT, B, 0, stream>>>(ei, bcur, ebuf);
    bucket_sort<<<NB, B, 0, stream>>>(ebuf, bbase, row_ptr, csr_src);

    // ---- layer 1 ----  (aggbuf free again after bucket_sort)
    gather6<<<blkN, B, 0, stream>>>(row_ptr, csr_src, x, aggbuf);
    mlp_stats<DIN><<<blkN, B, 0, stream>>>(aggbuf, hbuf16, w1a, b1a, w1b, b1b, partial);
    reduce_partial<<<RED_BLKS, B, 0, stream>>>(partial, blkN, partial2);
    finalize_stats<<<1, B, 0, stream>>>(partial2, g1, be1, ss1);

    // ---- layer 2 (fused gather+BN1+MLP): hbuf16 -> abuf16 ----
    fused_gin16<<<FUSED_BLOCKS, B, 0, stream>>>(row_ptr, csr_src, hbuf16, ss1,
                                                w2a, b2a, w2b, b2b, abuf16, partial);
    reduce_partial<<<RED_BLKS, B, 0, stream>>>(partial, FUSED_BLOCKS, partial2);
    finalize_stats<<<1, B, 0, stream>>>(partial2, g2, be2, ss2);

    // ---- layer 3 (fused): abuf16 -> hbuf16 ----
    fused_gin16<<<FUSED_BLOCKS, B, 0, stream>>>(row_ptr, csr_src, abuf16, ss2,
                                                w3a, b3a, w3b, b3b, hbuf16, partial);
    reduce_partial<<<RED_BLKS, B, 0, stream>>>(partial, FUSED_BLOCKS, partial2);
    finalize_stats<<<1, B, 0, stream>>>(partial2, g3, be3, ss3);

    // ---- pool (BN3 applied inline) + head ----
    pool2_aff<<<NG, 64, 0, stream>>>(hbuf16, gptr, ss3, emb);
    head_kernel<<<(NG + B - 1) / B, B, 0, stream>>>(emb, wb, bb, wm, bm, out);
}

// Round 8
// 304.911 us; speedup vs baseline: 3.1740x; 1.1973x over previous
//
#include <hip/hip_runtime.h>
#include <hip/hip_fp16.h>
#include <math.h>

// Problem constants (match reference)
#define NN 150000
#define NE 2400000
#define NG 1024
#define DIN 6
#define DH 32
#define DB 16
#define BN_EPS 1e-5f

#define MLP_BLOCKS ((NN + 255) / 256)   // 586  (layer-1 mlp)
#define FUSED_BLOCKS ((NN + 63) / 64)   // 2344 (fused layers 2/3, 64 nodes/block)
#define RED_BLKS 64                     // stage-1 reduction blocks

// bucket sort params
#define NB 512            // buckets
#define NPB 293           // nodes per bucket (512*293 = 150016 >= NN); NPB < 512 so 9 bits
#define SCH 4096          // edges per scatter block
#define EPB 16            // edges per thread in scatter
#define CAP 8192          // max edges per bucket (expected ~4690)
#define NSCAT ((NE + SCH - 1) / SCH)  // 586

// inclusive Hillis-Steele scan of 512 ints in LDS with 256 threads
#define SCAN512(scarr, t)                                     \
    for (int off = 1; off < 512; off <<= 1) {                 \
        int v0 = (t >= off) ? scarr[t - off] : 0;             \
        int v1 = scarr[t + 256 - off];                        \
        __syncthreads();                                      \
        if (t >= off) scarr[t] += v0;                         \
        scarr[t + 256] += v1;                                 \
        __syncthreads();                                      \
    }

__device__ inline void addh8(float* a, uint4 v) {
    const __half2* hp = (const __half2*)&v;
#pragma unroll
    for (int i = 0; i < 4; ++i) {
        float2 f = __half22float2(hp[i]);
        a[2 * i] += f.x; a[2 * i + 1] += f.y;
    }
}

// ================= bucket CSR build =================
__global__ void bucket_count(const int* __restrict__ ei, int* __restrict__ bcnt) {
    __shared__ int hist[NB];
    int t = threadIdx.x;
    for (int i = t; i < NB; i += 256) hist[i] = 0;
    __syncthreads();
    long e0 = (long)blockIdx.x * SCH;
#pragma unroll
    for (int k = 0; k < EPB; ++k) {
        long idx = e0 + k * 256 + t;
        if (idx < NE) atomicAdd(&hist[ei[NE + idx] / NPB], 1);
    }
    __syncthreads();
    for (int i = t; i < NB; i += 256)
        if (hist[i]) atomicAdd(&bcnt[i], hist[i]);
}

__global__ void bucket_scan(const int* __restrict__ bcnt,
                            int* __restrict__ bbase, int* __restrict__ bcur) {
    __shared__ int sc[NB];
    int t = threadIdx.x;
    int c0 = bcnt[t], c1 = bcnt[t + 256];
    sc[t] = c0; sc[t + 256] = c1;
    __syncthreads();
    SCAN512(sc, t);
    int e0 = sc[t] - c0, e1 = sc[t + 256] - c1;
    bbase[t] = e0; bbase[t + 256] = e1;
    bcur[t] = e0;  bcur[t + 256] = e1;
    if (t == 0) bbase[NB] = NE;
}

// block-local binning -> packed (src<<9|dst_local) writes into bucket regions
__global__ void bucket_scatter(const int* __restrict__ ei, int* __restrict__ bcur,
                               unsigned* __restrict__ ebuf) {
    __shared__ int hist[NB];
    __shared__ int sc[NB];
    __shared__ int lcur[NB];
    __shared__ int gbase[NB];
    __shared__ unsigned stage[SCH];
    __shared__ unsigned short stageb[SCH];
    int t = threadIdx.x;
    long e0 = (long)blockIdx.x * SCH;
    int s16[EPB], d16[EPB];
    for (int i = t; i < NB; i += 256) hist[i] = 0;
    __syncthreads();
#pragma unroll
    for (int k = 0; k < EPB; ++k) {
        long idx = e0 + k * 256 + t;
        if (idx < NE) {
            s16[k] = ei[idx];
            d16[k] = ei[NE + idx];
            atomicAdd(&hist[d16[k] / NPB], 1);
        } else d16[k] = -1;
    }
    __syncthreads();
    for (int i = t; i < NB; i += 256) sc[i] = hist[i];
    __syncthreads();
    SCAN512(sc, t);
    for (int i = t; i < NB; i += 256) lcur[i] = sc[i] - hist[i];
    __syncthreads();
#pragma unroll
    for (int k = 0; k < EPB; ++k) {
        if (d16[k] >= 0) {
            int b = d16[k] / NPB;
            int p = atomicAdd(&lcur[b], 1);
            stage[p] = ((unsigned)s16[k] << 9) | (unsigned)(d16[k] - b * NPB);
            stageb[p] = (unsigned short)b;
        }
    }
    __syncthreads();
    for (int i = t; i < NB; i += 256) {
        int h = hist[i];
        gbase[i] = h ? atomicAdd(&bcur[i], h) : 0;
    }
    __syncthreads();
    int cnt = (int)((NE - e0) < SCH ? (NE - e0) : SCH);
    for (int i = t; i < cnt; i += 256) {
        int b = stageb[i];
        ebuf[gbase[b] + (i - (sc[b] - hist[b]))] = stage[i];
    }
}

// per-bucket LDS counting sort -> csr_src + row_ptr (fully coalesced global I/O)
__global__ void bucket_sort(const unsigned* __restrict__ ebuf, const int* __restrict__ bbase,
                            int* __restrict__ row_ptr, int* __restrict__ csr_src) {
    __shared__ int deg[NB];
    __shared__ int sc[NB];
    __shared__ int cur[NB];
    __shared__ int srcbuf[CAP];
    int b = blockIdx.x, t = threadIdx.x;
    int node0 = b * NPB;
    int nlocal = (NN - node0) < NPB ? (NN - node0) : NPB;
    int ebase = bbase[b];
    int ecnt = bbase[b + 1] - ebase;
    if (ecnt > CAP) ecnt = CAP;
    for (int i = t; i < NB; i += 256) deg[i] = 0;
    __syncthreads();
    for (int i = t; i < ecnt; i += 256) {
        atomicAdd(&deg[ebuf[ebase + i] & 511u], 1);
    }
    __syncthreads();
    for (int i = t; i < NB; i += 256) sc[i] = deg[i];
    __syncthreads();
    SCAN512(sc, t);
    for (int j = t; j < nlocal; j += 256) {
        int st = sc[j] - deg[j];
        row_ptr[node0 + j] = ebase + st;
        cur[j] = st;
    }
    if (b == NB - 1 && t == 0) row_ptr[NN] = NE;
    __syncthreads();
    for (int i = t; i < ecnt; i += 256) {
        unsigned v = ebuf[ebase + i];
        int p = atomicAdd(&cur[v & 511u], 1);
        srcbuf[p] = (int)(v >> 9);
    }
    __syncthreads();
    for (int i = t; i < ecnt; i += 256) csr_src[ebase + i] = srcbuf[i];
}

// ======= graph boundaries via binary search (batch is sorted) =======
__global__ void gbounds(const int* __restrict__ bat, int* __restrict__ gptr) {
    int g = blockIdx.x * blockDim.x + threadIdx.x;
    if (g > NG) return;
    int lo = 0, hi = NN;
    while (lo < hi) {
        int mid = (lo + hi) >> 1;
        if (bat[mid] < g) lo = mid + 1; else hi = mid;
    }
    gptr[g] = lo;
}

// ================= layer 1: gather (6ch, fp32 input x) =================
__global__ void gather6(const int* __restrict__ row_ptr, const int* __restrict__ csr_src,
                        const float* __restrict__ x, float* __restrict__ agg) {
    int node = blockIdx.x * blockDim.x + threadIdx.x;
    if (node >= NN) return;
    int beg = row_ptr[node], end = row_ptr[node + 1];
    const float2* xs = (const float2*)(x + (long)node * DIN);
    float2 a0 = xs[0], a1 = xs[1], a2 = xs[2];   // self term
    for (int e = beg; e < end; ++e) {
        int s = csr_src[e];
        const float2* p = (const float2*)(x + (long)s * DIN);
        float2 b0 = p[0], b1 = p[1], b2 = p[2];
        a0.x += b0.x; a0.y += b0.y;
        a1.x += b1.x; a1.y += b1.y;
        a2.x += b2.x; a2.y += b2.y;
    }
    float2* o = (float2*)(agg + (long)node * DIN);
    o[0] = a0; o[1] = a1; o[2] = a2;
}

// ======== layer 1 MLP + relu + BN-stat partials; fp16 output ========
template <int IN>
__global__ void mlp_stats(const float* __restrict__ agg,
                          __half* __restrict__ out,
                          const float* __restrict__ w1, const float* __restrict__ b1,
                          const float* __restrict__ w2, const float* __restrict__ b2,
                          float* __restrict__ partial /* [gridDim][64] */) {
    __shared__ float sw1[IN * DH];
    __shared__ float sw2[DH * DH];
    __shared__ float sb1[DH];
    __shared__ float sb2[DH];
    __shared__ float bsum[DH];
    __shared__ float bsq[DH];
    int t = threadIdx.x;
    for (int i = t; i < IN * DH; i += blockDim.x) sw1[i] = w1[i];
    for (int i = t; i < DH * DH; i += blockDim.x) sw2[i] = w2[i];
    if (t < DH) { sb1[t] = b1[t]; sb2[t] = b2[t]; bsum[t] = 0.f; bsq[t] = 0.f; }
    __syncthreads();

    int node = blockIdx.x * blockDim.x + t;
    bool valid = node < NN;

    float a[IN];
    if (valid) {
        const float* ar = agg + (long)node * IN;
#pragma unroll
        for (int k = 0; k < IN; ++k) a[k] = ar[k];
    } else {
#pragma unroll
        for (int k = 0; k < IN; ++k) a[k] = 0.f;
    }

    float u[DH];
#pragma unroll
    for (int j = 0; j < DH; ++j) {
        float acc = sb1[j];
#pragma unroll
        for (int k = 0; k < IN; ++k) acc += a[k] * sw1[k * DH + j];
        u[j] = fmaxf(acc, 0.f);
    }

    float r[DH];
#pragma unroll
    for (int j = 0; j < DH; ++j) {
        float acc = sb2[j];
#pragma unroll
        for (int k = 0; k < DH; ++k) acc += u[k] * sw2[k * DH + j];
        r[j] = valid ? fmaxf(acc, 0.f) : 0.f;
    }

    if (valid) {
        uint4* o = (uint4*)(out + (long)node * DH);
#pragma unroll
        for (int q = 0; q < 4; ++q) {
            uint4 v;
            unsigned* vp = (unsigned*)&v;
#pragma unroll
            for (int i = 0; i < 4; ++i) {
                __half2 hh = __floats2half2_rn(r[q * 8 + 2 * i], r[q * 8 + 2 * i + 1]);
                vp[i] = *(unsigned*)&hh;
            }
            o[q] = v;
        }
    }

    int lane = t & 63;
#pragma unroll
    for (int j = 0; j < DH; ++j) {
        float s = r[j];
        float q = r[j] * r[j];
        for (int o = 32; o > 0; o >>= 1) {
            s += __shfl_xor(s, o);
            q += __shfl_xor(q, o);
        }
        if (lane == 0) {
            atomicAdd(&bsum[j], s);   // LDS atomic, cheap
            atomicAdd(&bsq[j], q);
        }
    }
    __syncthreads();
    if (t < 2 * DH) {
        float v = (t < DH) ? bsum[t] : bsq[t - DH];
        partial[(long)blockIdx.x * (2 * DH) + t] = v;
    }
}

// ======== fused layers 2/3 (fp16 h): gather + MLP via quad-shuffle, no big LDS ========
// 64 nodes / block, 4 threads / node (8 channels each). in/out distinct buffers.
__global__ void __launch_bounds__(256) fused_gin16(
    const int* __restrict__ row_ptr, const int* __restrict__ csr_src,
    const __half* __restrict__ h, const float* __restrict__ ss,
    const float* __restrict__ w1, const float* __restrict__ b1,
    const float* __restrict__ w2, const float* __restrict__ b2,
    __half* __restrict__ out, float* __restrict__ partial /* [gridDim][64] */) {
    __shared__ float sw1[DH * DH];
    __shared__ float sw2[DH * DH];
    __shared__ float sb1[DH];
    __shared__ float sb2[DH];
    __shared__ float bsum[DH];
    __shared__ float bsq[DH];
    int t = threadIdx.x;
    for (int i = t; i < DH * DH; i += 256) { sw1[i] = w1[i]; sw2[i] = w2[i]; }
    if (t < DH) { sb1[t] = b1[t]; sb2[t] = b2[t]; bsum[t] = 0.f; bsq[t] = 0.f; }
    __syncthreads();

    int nl = t >> 2, sub = t & 3;
    int node = blockIdx.x * 64 + nl;
    bool valid = node < NN;
    int j0 = sub * 8;
    int qb = t & ~3;      // quad base lane (same wave)

    // ---- gather (4 threads/node, 8 fp16 ch each = 16B loads), 4-deep unroll ----
    const uint4* hb = (const uint4*)h;   // node row = 4 uint4
    float a[8] = {0.f, 0.f, 0.f, 0.f, 0.f, 0.f, 0.f, 0.f};
    int beg = 0, end = 0;
    if (valid) {
        beg = row_ptr[node];
        end = row_ptr[node + 1];
        addh8(a, hb[(long)node * 4 + sub]);     // self term
    }
    int e = beg;
    int nrem = end - beg;
    for (int i = 0; i < (nrem & ~3); i += 4) {
        int s0 = csr_src[e], s1 = csr_src[e + 1], s2 = csr_src[e + 2], s3 = csr_src[e + 3];
        e += 4;
        uint4 v0 = hb[(long)s0 * 4 + sub];
        uint4 v1 = hb[(long)s1 * 4 + sub];
        uint4 v2 = hb[(long)s2 * 4 + sub];
        uint4 v3 = hb[(long)s3 * 4 + sub];
        addh8(a, v0); addh8(a, v1); addh8(a, v2); addh8(a, v3);
    }
    for (; e < end; ++e) addh8(a, hb[(long)csr_src[e] * 4 + sub]);

    // ---- BN affine fold (stays in registers) ----
    float cnt = (float)(end - beg + 1);
#pragma unroll
    for (int i = 0; i < 8; ++i)
        a[i] = a[i] * ss[j0 + i] + cnt * ss[DH + j0 + i];

    // ---- MLP layer A via quad-shuffle exchange ----
    float u[8];
#pragma unroll
    for (int i = 0; i < 8; ++i) u[i] = sb1[j0 + i];
#pragma unroll
    for (int q = 0; q < 4; ++q) {
#pragma unroll
        for (int i = 0; i < 8; ++i) {
            float ak = __shfl(a[i], qb + q);
            int k = q * 8 + i;
            const float4* w4 = (const float4*)&sw1[k * DH + j0];
            float4 wa = w4[0], wb = w4[1];
            u[0] += ak * wa.x; u[1] += ak * wa.y; u[2] += ak * wa.z; u[3] += ak * wa.w;
            u[4] += ak * wb.x; u[5] += ak * wb.y; u[6] += ak * wb.z; u[7] += ak * wb.w;
        }
    }
#pragma unroll
    for (int i = 0; i < 8; ++i) u[i] = fmaxf(u[i], 0.f);

    // ---- MLP layer B via quad-shuffle exchange ----
    float r[8];
#pragma unroll
    for (int i = 0; i < 8; ++i) r[i] = sb2[j0 + i];
#pragma unroll
    for (int q = 0; q < 4; ++q) {
#pragma unroll
        for (int i = 0; i < 8; ++i) {
            float uk = __shfl(u[i], qb + q);
            int k = q * 8 + i;
            const float4* w4 = (const float4*)&sw2[k * DH + j0];
            float4 wa = w4[0], wb = w4[1];
            r[0] += uk * wa.x; r[1] += uk * wa.y; r[2] += uk * wa.z; r[3] += uk * wa.w;
            r[4] += uk * wb.x; r[5] += uk * wb.y; r[6] += uk * wb.z; r[7] += uk * wb.w;
        }
    }
#pragma unroll
    for (int i = 0; i < 8; ++i) r[i] = valid ? fmaxf(r[i], 0.f) : 0.f;

    if (valid) {
        uint4 o;
        unsigned* op = (unsigned*)&o;
#pragma unroll
        for (int i = 0; i < 4; ++i) {
            __half2 hh = __floats2half2_rn(r[2 * i], r[2 * i + 1]);
            op[i] = *(unsigned*)&hh;
        }
        ((uint4*)out)[(long)node * 4 + sub] = o;
    }

    // ---- stats: butterfly over the 16 nodes in this wave, then LDS atomic ----
    float s[8], q[8];
#pragma unroll
    for (int i = 0; i < 8; ++i) { s[i] = r[i]; q[i] = r[i] * r[i]; }
#pragma unroll
    for (int o = 4; o < 64; o <<= 1) {
#pragma unroll
        for (int i = 0; i < 8; ++i) {
            s[i] += __shfl_xor(s[i], o);
            q[i] += __shfl_xor(q[i], o);
        }
    }
    if ((t & 63) < 4) {
#pragma unroll
        for (int i = 0; i < 8; ++i) {
            atomicAdd(&bsum[j0 + i], s[i]);
            atomicAdd(&bsq[j0 + i], q[i]);
        }
    }
    __syncthreads();
    if (t < 2 * DH) {
        float v = (t < DH) ? bsum[t] : bsq[t - DH];
        partial[(long)blockIdx.x * (2 * DH) + t] = v;
    }
}

// ===== stage 1: fold partial[nblk][64] -> partial2[RED_BLKS][64], coalesced =====
__global__ void reduce_partial(const float* __restrict__ partial, int nblk,
                               float* __restrict__ partial2) {
    __shared__ float sred[4][64];
    int t = threadIdx.x;           // 256
    int ch = t & 63, sub = t >> 6;
    int chunk = (nblk + RED_BLKS - 1) / RED_BLKS;
    int start = blockIdx.x * chunk;
    int end = start + chunk; if (end > nblk) end = nblk;
    float acc = 0.f;
    for (int r = start + sub; r < end; r += 4)
        acc += partial[(long)r * 64 + ch];
    sred[sub][ch] = acc;
    __syncthreads();
    if (t < 64)
        partial2[(long)blockIdx.x * 64 + t] =
            sred[0][t] + sred[1][t] + sred[2][t] + sred[3][t];
}

// ===== stage 2: fold partial2 + finalize BN scale/shift =====
__global__ void finalize_stats(const float* __restrict__ partial2,
                               const float* __restrict__ g, const float* __restrict__ be,
                               float* __restrict__ ss) {
    __shared__ float sred[4][64];
    __shared__ float sums[64];
    int t = threadIdx.x;           // 256
    int ch = t & 63, sub = t >> 6;
    float acc = 0.f;
    for (int r = sub; r < RED_BLKS; r += 4) acc += partial2[(long)r * 64 + ch];
    sred[sub][ch] = acc;
    __syncthreads();
    if (t < 64) sums[t] = sred[0][t] + sred[1][t] + sred[2][t] + sred[3][t];
    __syncthreads();
    if (t < DH) {
        float mu = sums[t] * (1.0f / NN);
        float var = sums[DH + t] * (1.0f / NN) - mu * mu;
        float sc = g[t] * rsqrtf(var + BN_EPS);
        ss[t] = sc;
        ss[DH + t] = be[t] - mu * sc;
    }
}

// ====== per-graph mean pool of BN(h), affine folded; vectorized uint4 loads ======
__global__ void pool2_aff(const __half* __restrict__ h, const int* __restrict__ gptr,
                          const float* __restrict__ ss, float* __restrict__ emb) {
    int g = blockIdx.x;
    int t = threadIdx.x;           // 64 threads
    int beg = gptr[g], end = gptr[g + 1];
    int sub = t & 3, nt = t >> 2;  // 16 node slots x 4 quarters
    const uint4* hb = (const uint4*)h;
    float acc[8] = {0.f, 0.f, 0.f, 0.f, 0.f, 0.f, 0.f, 0.f};
    for (int n = beg + nt; n < end; n += 16) addh8(acc, hb[(long)n * 4 + sub]);
#pragma unroll
    for (int o = 4; o < 64; o <<= 1) {
#pragma unroll
        for (int i = 0; i < 8; ++i) acc[i] += __shfl_xor(acc[i], o);
    }
    if (t < 4) {
        int c = end - beg;
        int j0 = t * 8;
        float inv = (c > 0) ? 1.0f / (float)c : 0.f;
#pragma unroll
        for (int i = 0; i < 8; ++i) {
            float val = (c > 0) ? ss[j0 + i] * (acc[i] * inv) + ss[DH + j0 + i] : 0.f;
            emb[(long)g * DH + j0 + i] = val;
        }
    }
}

// ================= head: emb -> 16 relu -> 1 sigmoid =================
__global__ void head_kernel(const float* __restrict__ emb,
                            const float* __restrict__ wb, const float* __restrict__ bb,
                            const float* __restrict__ wm, const float* __restrict__ bm,
                            float* __restrict__ out) {
    __shared__ float swb[DH * DB];
    __shared__ float sbb[DB];
    __shared__ float swm[DB];
    int t = threadIdx.x;
    for (int i = t; i < DH * DB; i += blockDim.x) swb[i] = wb[i];
    if (t < DB) { sbb[t] = bb[t]; swm[t] = wm[t]; }
    __syncthreads();

    int g = blockIdx.x * blockDim.x + t;
    if (g >= NG) return;
    float e[DH];
#pragma unroll
    for (int d = 0; d < DH; ++d) e[d] = emb[(long)g * DH + d];
    float acc = bm[0];
#pragma unroll
    for (int j = 0; j < DB; ++j) {
        float z = sbb[j];
#pragma unroll
        for (int d = 0; d < DH; ++d) z += e[d] * swb[d * DB + j];
        z = fmaxf(z, 0.f);
        acc += z * swm[j];
    }
    out[g] = 1.0f / (1.0f + expf(-acc));
}

extern "C" void kernel_launch(void* const* d_in, const int* in_sizes, int n_in,
                              void* d_out, int out_size, void* d_ws, size_t ws_size,
                              hipStream_t stream) {
    const float* x   = (const float*)d_in[0];
    const int*   ei  = (const int*)d_in[1];
    const int*   bat = (const int*)d_in[2];
    const float* w1a = (const float*)d_in[3];  const float* b1a = (const float*)d_in[4];
    const float* w1b = (const float*)d_in[5];  const float* b1b = (const float*)d_in[6];
    const float* g1  = (const float*)d_in[7];  const float* be1 = (const float*)d_in[8];
    const float* w2a = (const float*)d_in[9];  const float* b2a = (const float*)d_in[10];
    const float* w2b = (const float*)d_in[11]; const float* b2b = (const float*)d_in[12];
    const float* g2  = (const float*)d_in[13]; const float* be2 = (const float*)d_in[14];
    const float* w3a = (const float*)d_in[15]; const float* b3a = (const float*)d_in[16];
    const float* w3b = (const float*)d_in[17]; const float* b3b = (const float*)d_in[18];
    const float* g3  = (const float*)d_in[19]; const float* be3 = (const float*)d_in[20];
    const float* wb  = (const float*)d_in[21]; const float* bb  = (const float*)d_in[22];
    const float* wm  = (const float*)d_in[23]; const float* bm  = (const float*)d_in[24];
    float* out = (float*)d_out;

    // ---- workspace layout (4-byte units) ----
    char* wsb = (char*)d_ws;
    float* hbuf    = (float*)wsb;                               // NN*DH fp32 region; used as fp16 h (half the bytes)
    float* aggbuf  = hbuf + (long)NN * DH;                      // NN*DH region (aliased: ebuf uint[NE]; layer-1 fp32 agg; fp16 ping-pong)
    unsigned* ebuf = (unsigned*)aggbuf;
    int*   csr_src = (int*)(aggbuf + (long)NN * DH);            // NE
    int*   row_ptr = csr_src + NE;                              // NN+1
    int*   bbase   = row_ptr + NN + 1;                          // NB+1
    int*   bcur    = bbase + NB + 1;                            // NB
    int*   gptr    = bcur + NB;                                 // NG+1
    float* emb     = (float*)(gptr + NG + 1);                   // NG*DH
    float* ss1     = emb + (long)NG * DH;                       // 64 (BN scale/shift)
    float* ss2     = ss1 + 2 * DH;                              // 64
    float* ss3     = ss2 + 2 * DH;                              // 64
    float* partial2= ss3 + 2 * DH;                              // RED_BLKS*64
    float* partial = partial2 + (long)RED_BLKS * 64;            // FUSED_BLOCKS*64 (>= MLP_BLOCKS)
    int*   bcnt    = (int*)(partial + (long)FUSED_BLOCKS * 2 * DH); // NB (zeroed)

    __half* hbuf16 = (__half*)hbuf;
    __half* abuf16 = (__half*)aggbuf;

    hipMemsetAsync(bcnt, 0, (size_t)NB * 4, stream);

    const int B = 256;
    int blkN = (NN + B - 1) / B;        // == MLP_BLOCKS

    // ---- CSR via two-level bucket sort (all random access in LDS) ----
    bucket_count<<<NSCAT, B, 0, stream>>>(ei, bcnt);
    gbounds<<<(NG + 1 + B - 1) / B, B, 0, stream>>>(bat, gptr);
    bucket_scan<<<1, B, 0, stream>>>(bcnt, bbase, bcur);
    bucket_scatter<<<NSCAT, B, 0, stream>>>(ei, bcur, ebuf);
    bucket_sort<<<NB, B, 0, stream>>>(ebuf, bbase, row_ptr, csr_src);

    // ---- layer 1 ----  (aggbuf free again after bucket_sort)
    gather6<<<blkN, B, 0, stream>>>(row_ptr, csr_src, x, aggbuf);
    mlp_stats<DIN><<<blkN, B, 0, stream>>>(aggbuf, hbuf16, w1a, b1a, w1b, b1b, partial);
    reduce_partial<<<RED_BLKS, B, 0, stream>>>(partial, blkN, partial2);
    finalize_stats<<<1, B, 0, stream>>>(partial2, g1, be1, ss1);

    // ---- layer 2 (fused gather+BN1+MLP): hbuf16 -> abuf16 ----
    fused_gin16<<<FUSED_BLOCKS, B, 0, stream>>>(row_ptr, csr_src, hbuf16, ss1,
                                                w2a, b2a, w2b, b2b, abuf16, partial);
    reduce_partial<<<RED_BLKS, B, 0, stream>>>(partial, FUSED_BLOCKS, partial2);
    finalize_stats<<<1, B, 0, stream>>>(partial2, g2, be2, ss2);

    // ---- layer 3 (fused): abuf16 -> hbuf16 ----
    fused_gin16<<<FUSED_BLOCKS, B, 0, stream>>>(row_ptr, csr_src, abuf16, ss2,
                                                w3a, b3a, w3b, b3b, hbuf16, partial);
    reduce_partial<<<RED_BLKS, B, 0, stream>>>(partial, FUSED_BLOCKS, partial2);
    finalize_stats<<<1, B, 0, stream>>>(partial2, g3, be3, ss3);

    // ---- pool (BN3 applied inline) + head ----
    pool2_aff<<<NG, 64, 0, stream>>>(hbuf16, gptr, ss3, emb);
    head_kernel<<<(NG + B - 1) / B, B, 0, stream>>>(emb, wb, bb, wm, bm, out);
}

// Round 9
// 260.562 us; speedup vs baseline: 3.7142x; 1.1702x over previous
//
#include <hip/hip_runtime.h>
#include <hip/hip_fp16.h>
#include <math.h>

// Problem constants (match reference)
#define NN 150000
#define NE 2400000
#define NG 1024
#define DIN 6
#define DH 32
#define DB 16
#define BN_EPS 1e-5f

#define L1_BLOCKS ((NN + 255) / 256)    // 586  (fused layer 1)
#define FUSED_BLOCKS ((NN + 63) / 64)   // 2344 (fused layers 2/3, 64 nodes/block)
#define RED_BLKS 64                     // stage-1 reduction blocks

// bucket sort params
#define NB 512            // buckets
#define NPB 293           // nodes per bucket (512*293 = 150016 >= NN); NPB < 512 so 9 bits
#define SCH 4096          // edges per scatter block
#define EPB 16            // edges per thread in scatter
#define CAP 8192          // fixed region per bucket (expected ~4690 edges, +51 sigma headroom)
#define NSCAT ((NE + SCH - 1) / SCH)  // 586

// inclusive Hillis-Steele scan of 512 ints in LDS with 256 threads
#define SCAN512(scarr, t)                                     \
    for (int off = 1; off < 512; off <<= 1) {                 \
        int v0 = (t >= off) ? scarr[t - off] : 0;             \
        int v1 = scarr[t + 256 - off];                        \
        __syncthreads();                                      \
        if (t >= off) scarr[t] += v0;                         \
        scarr[t + 256] += v1;                                 \
        __syncthreads();                                      \
    }

__device__ inline void addh8(float* a, uint4 v) {
    const __half2* hp = (const __half2*)&v;
#pragma unroll
    for (int i = 0; i < 4; ++i) {
        float2 f = __half22float2(hp[i]);
        a[2 * i] += f.x; a[2 * i + 1] += f.y;
    }
}

// ===== init: bucket cursors (fixed stride) + graph bounds via binary search =====
__global__ void init_misc(const int* __restrict__ bat, int* __restrict__ bcur,
                          int* __restrict__ gptr) {
    int i = blockIdx.x * blockDim.x + threadIdx.x;
    if (i < NB) bcur[i] = i * CAP;
    if (i <= NG) {
        int lo = 0, hi = NN;
        while (lo < hi) {
            int mid = (lo + hi) >> 1;
            if (bat[mid] < i) lo = mid + 1; else hi = mid;
        }
        gptr[i] = lo;
    }
}

// block-local binning -> packed (src<<9|dst_local) writes into fixed bucket regions
__global__ void bucket_scatter(const int* __restrict__ ei, int* __restrict__ bcur,
                               unsigned* __restrict__ ebuf) {
    __shared__ int hist[NB];
    __shared__ int sc[NB];
    __shared__ int lcur[NB];
    __shared__ int gbase[NB];
    __shared__ unsigned stage[SCH];
    __shared__ unsigned short stageb[SCH];
    int t = threadIdx.x;
    long e0 = (long)blockIdx.x * SCH;
    int s16[EPB], d16[EPB];
    for (int i = t; i < NB; i += 256) hist[i] = 0;
    __syncthreads();
#pragma unroll
    for (int k = 0; k < EPB; ++k) {
        long idx = e0 + k * 256 + t;
        if (idx < NE) {
            s16[k] = ei[idx];
            d16[k] = ei[NE + idx];
            atomicAdd(&hist[d16[k] / NPB], 1);
        } else d16[k] = -1;
    }
    __syncthreads();
    for (int i = t; i < NB; i += 256) sc[i] = hist[i];
    __syncthreads();
    SCAN512(sc, t);
    for (int i = t; i < NB; i += 256) lcur[i] = sc[i] - hist[i];
    __syncthreads();
#pragma unroll
    for (int k = 0; k < EPB; ++k) {
        if (d16[k] >= 0) {
            int b = d16[k] / NPB;
            int p = atomicAdd(&lcur[b], 1);
            stage[p] = ((unsigned)s16[k] << 9) | (unsigned)(d16[k] - b * NPB);
            stageb[p] = (unsigned short)b;
        }
    }
    __syncthreads();
    for (int i = t; i < NB; i += 256) {
        int h = hist[i];
        gbase[i] = h ? atomicAdd(&bcur[i], h) : 0;
    }
    __syncthreads();
    int cnt = (int)((NE - e0) < SCH ? (NE - e0) : SCH);
    for (int i = t; i < cnt; i += 256) {
        int b = stageb[i];
        ebuf[gbase[b] + (i - (sc[b] - hist[b]))] = stage[i];
    }
}

// per-bucket LDS counting sort -> csr_src (fixed stride) + rbeg/rend per node
__global__ void bucket_sort(const unsigned* __restrict__ ebuf, const int* __restrict__ bcur,
                            int* __restrict__ rbeg, int* __restrict__ rend,
                            int* __restrict__ csr_src) {
    __shared__ int deg[NB];
    __shared__ int sc[NB];
    __shared__ int cur[NB];
    __shared__ int srcbuf[CAP];
    int b = blockIdx.x, t = threadIdx.x;
    int node0 = b * NPB;
    int nlocal = (NN - node0) < NPB ? (NN - node0) : NPB;
    int ebase = b * CAP;
    int ecnt = bcur[b] - ebase;
    if (ecnt > CAP) ecnt = CAP;
    for (int i = t; i < NB; i += 256) deg[i] = 0;
    __syncthreads();
    for (int i = t; i < ecnt; i += 256) {
        atomicAdd(&deg[ebuf[ebase + i] & 511u], 1);
    }
    __syncthreads();
    for (int i = t; i < NB; i += 256) sc[i] = deg[i];
    __syncthreads();
    SCAN512(sc, t);
    for (int j = t; j < nlocal; j += 256) {
        int st = sc[j] - deg[j];
        rbeg[node0 + j] = ebase + st;
        rend[node0 + j] = ebase + st + deg[j];
        cur[j] = st;
    }
    __syncthreads();
    for (int i = t; i < ecnt; i += 256) {
        unsigned v = ebuf[ebase + i];
        int p = atomicAdd(&cur[v & 511u], 1);
        srcbuf[p] = (int)(v >> 9);
    }
    __syncthreads();
    for (int i = t; i < ecnt; i += 256) csr_src[ebase + i] = srcbuf[i];
}

// ======== fused layer 1: gather(6ch fp32) + MLP(6->32relu->32) + relu + stats ========
__global__ void fused_gin6(const int* __restrict__ rbeg, const int* __restrict__ rend,
                           const int* __restrict__ csr_src, const float* __restrict__ x,
                           const float* __restrict__ w1, const float* __restrict__ b1,
                           const float* __restrict__ w2, const float* __restrict__ b2,
                           __half* __restrict__ out, float* __restrict__ partial) {
    __shared__ float sw1[DIN * DH];
    __shared__ float sw2[DH * DH];
    __shared__ float sb1[DH];
    __shared__ float sb2[DH];
    __shared__ float bsum[DH];
    __shared__ float bsq[DH];
    int t = threadIdx.x;
    for (int i = t; i < DIN * DH; i += 256) sw1[i] = w1[i];
    for (int i = t; i < DH * DH; i += 256) sw2[i] = w2[i];
    if (t < DH) { sb1[t] = b1[t]; sb2[t] = b2[t]; bsum[t] = 0.f; bsq[t] = 0.f; }
    __syncthreads();

    int node = blockIdx.x * 256 + t;
    bool valid = node < NN;

    float a0 = 0.f, a1 = 0.f, a2 = 0.f, a3 = 0.f, a4 = 0.f, a5 = 0.f;
    int beg = 0, end = 0;
    if (valid) {
        beg = rbeg[node]; end = rend[node];
        const float2* xs = (const float2*)(x + (long)node * DIN);
        float2 p0 = xs[0], p1 = xs[1], p2 = xs[2];
        a0 = p0.x; a1 = p0.y; a2 = p1.x; a3 = p1.y; a4 = p2.x; a5 = p2.y;
    }
    for (int e = beg; e < end; ++e) {
        int s = csr_src[e];
        const float2* p = (const float2*)(x + (long)s * DIN);
        float2 b0 = p[0], b1v = p[1], b2v = p[2];
        a0 += b0.x; a1 += b0.y; a2 += b1v.x; a3 += b1v.y; a4 += b2v.x; a5 += b2v.y;
    }

    float u[DH];
#pragma unroll
    for (int j = 0; j < DH; ++j) {
        float acc = sb1[j];
        acc += a0 * sw1[0 * DH + j] + a1 * sw1[1 * DH + j] + a2 * sw1[2 * DH + j];
        acc += a3 * sw1[3 * DH + j] + a4 * sw1[4 * DH + j] + a5 * sw1[5 * DH + j];
        u[j] = fmaxf(acc, 0.f);
    }

    float r[DH];
#pragma unroll
    for (int j = 0; j < DH; ++j) {
        float acc = sb2[j];
#pragma unroll
        for (int k = 0; k < DH; ++k) acc += u[k] * sw2[k * DH + j];
        r[j] = valid ? fmaxf(acc, 0.f) : 0.f;
    }

    if (valid) {
        uint4* o = (uint4*)(out + (long)node * DH);
#pragma unroll
        for (int q = 0; q < 4; ++q) {
            uint4 v;
            unsigned* vp = (unsigned*)&v;
#pragma unroll
            for (int i = 0; i < 4; ++i) {
                __half2 hh = __floats2half2_rn(r[q * 8 + 2 * i], r[q * 8 + 2 * i + 1]);
                vp[i] = *(unsigned*)&hh;
            }
            o[q] = v;
        }
    }

    int lane = t & 63;
#pragma unroll
    for (int j = 0; j < DH; ++j) {
        float s = r[j];
        float q = r[j] * r[j];
        for (int o = 32; o > 0; o >>= 1) {
            s += __shfl_xor(s, o);
            q += __shfl_xor(q, o);
        }
        if (lane == 0) {
            atomicAdd(&bsum[j], s);
            atomicAdd(&bsq[j], q);
        }
    }
    __syncthreads();
    if (t < 2 * DH) {
        float v = (t < DH) ? bsum[t] : bsq[t - DH];
        partial[(long)blockIdx.x * (2 * DH) + t] = v;
    }
}

// ======== fused layers 2/3 (fp16 h): gather + MLP via quad-shuffle ========
// 64 nodes / block, 4 threads / node (8 channels each). in/out distinct buffers.
__global__ void __launch_bounds__(256) fused_gin16(
    const int* __restrict__ rbeg, const int* __restrict__ rend,
    const int* __restrict__ csr_src,
    const __half* __restrict__ h, const float* __restrict__ ss,
    const float* __restrict__ w1, const float* __restrict__ b1,
    const float* __restrict__ w2, const float* __restrict__ b2,
    __half* __restrict__ out, float* __restrict__ partial /* [gridDim][64] */) {
    __shared__ float sw1[DH * DH];
    __shared__ float sw2[DH * DH];
    __shared__ float sb1[DH];
    __shared__ float sb2[DH];
    __shared__ float bsum[DH];
    __shared__ float bsq[DH];
    int t = threadIdx.x;
    for (int i = t; i < DH * DH; i += 256) { sw1[i] = w1[i]; sw2[i] = w2[i]; }
    if (t < DH) { sb1[t] = b1[t]; sb2[t] = b2[t]; bsum[t] = 0.f; bsq[t] = 0.f; }
    __syncthreads();

    int nl = t >> 2, sub = t & 3;
    int node = blockIdx.x * 64 + nl;
    bool valid = node < NN;
    int j0 = sub * 8;
    int qb = t & ~3;      // quad base lane (same wave)

    // ---- gather (4 threads/node, 8 fp16 ch each = 16B loads), 4-deep unroll ----
    const uint4* hb = (const uint4*)h;   // node row = 4 uint4
    float a[8] = {0.f, 0.f, 0.f, 0.f, 0.f, 0.f, 0.f, 0.f};
    int beg = 0, end = 0;
    if (valid) {
        beg = rbeg[node]; end = rend[node];
        addh8(a, hb[(long)node * 4 + sub]);     // self term
    }
    int e = beg;
    int nrem = end - beg;
    for (int i = 0; i < (nrem & ~3); i += 4) {
        int s0 = csr_src[e], s1 = csr_src[e + 1], s2 = csr_src[e + 2], s3 = csr_src[e + 3];
        e += 4;
        uint4 v0 = hb[(long)s0 * 4 + sub];
        uint4 v1 = hb[(long)s1 * 4 + sub];
        uint4 v2 = hb[(long)s2 * 4 + sub];
        uint4 v3 = hb[(long)s3 * 4 + sub];
        addh8(a, v0); addh8(a, v1); addh8(a, v2); addh8(a, v3);
    }
    for (; e < end; ++e) addh8(a, hb[(long)csr_src[e] * 4 + sub]);

    // ---- BN affine fold (stays in registers) ----
    float cnt = (float)(end - beg + 1);
#pragma unroll
    for (int i = 0; i < 8; ++i)
        a[i] = a[i] * ss[j0 + i] + cnt * ss[DH + j0 + i];

    // ---- MLP layer A via quad-shuffle exchange ----
    float u[8];
#pragma unroll
    for (int i = 0; i < 8; ++i) u[i] = sb1[j0 + i];
#pragma unroll
    for (int q = 0; q < 4; ++q) {
#pragma unroll
        for (int i = 0; i < 8; ++i) {
            float ak = __shfl(a[i], qb + q);
            int k = q * 8 + i;
            const float4* w4 = (const float4*)&sw1[k * DH + j0];
            float4 wa = w4[0], wb = w4[1];
            u[0] += ak * wa.x; u[1] += ak * wa.y; u[2] += ak * wa.z; u[3] += ak * wa.w;
            u[4] += ak * wb.x; u[5] += ak * wb.y; u[6] += ak * wb.z; u[7] += ak * wb.w;
        }
    }
#pragma unroll
    for (int i = 0; i < 8; ++i) u[i] = fmaxf(u[i], 0.f);

    // ---- MLP layer B via quad-shuffle exchange ----
    float r[8];
#pragma unroll
    for (int i = 0; i < 8; ++i) r[i] = sb2[j0 + i];
#pragma unroll
    for (int q = 0; q < 4; ++q) {
#pragma unroll
        for (int i = 0; i < 8; ++i) {
            float uk = __shfl(u[i], qb + q);
            int k = q * 8 + i;
            const float4* w4 = (const float4*)&sw2[k * DH + j0];
            float4 wa = w4[0], wb = w4[1];
            r[0] += uk * wa.x; r[1] += uk * wa.y; r[2] += uk * wa.z; r[3] += uk * wa.w;
            r[4] += uk * wb.x; r[5] += uk * wb.y; r[6] += uk * wb.z; r[7] += uk * wb.w;
        }
    }
#pragma unroll
    for (int i = 0; i < 8; ++i) r[i] = valid ? fmaxf(r[i], 0.f) : 0.f;

    if (valid) {
        uint4 o;
        unsigned* op = (unsigned*)&o;
#pragma unroll
        for (int i = 0; i < 4; ++i) {
            __half2 hh = __floats2half2_rn(r[2 * i], r[2 * i + 1]);
            op[i] = *(unsigned*)&hh;
        }
        ((uint4*)out)[(long)node * 4 + sub] = o;
    }

    // ---- stats: butterfly over the 16 nodes in this wave, then LDS atomic ----
    float s[8], q[8];
#pragma unroll
    for (int i = 0; i < 8; ++i) { s[i] = r[i]; q[i] = r[i] * r[i]; }
#pragma unroll
    for (int o = 4; o < 64; o <<= 1) {
#pragma unroll
        for (int i = 0; i < 8; ++i) {
            s[i] += __shfl_xor(s[i], o);
            q[i] += __shfl_xor(q[i], o);
        }
    }
    if ((t & 63) < 4) {
#pragma unroll
        for (int i = 0; i < 8; ++i) {
            atomicAdd(&bsum[j0 + i], s[i]);
            atomicAdd(&bsq[j0 + i], q[i]);
        }
    }
    __syncthreads();
    if (t < 2 * DH) {
        float v = (t < DH) ? bsum[t] : bsq[t - DH];
        partial[(long)blockIdx.x * (2 * DH) + t] = v;
    }
}

// ===== stage 1: fold partial[nblk][64] -> partial2[RED_BLKS][64], coalesced =====
__global__ void reduce_partial(const float* __restrict__ partial, int nblk,
                               float* __restrict__ partial2) {
    __shared__ float sred[4][64];
    int t = threadIdx.x;           // 256
    int ch = t & 63, sub = t >> 6;
    int chunk = (nblk + RED_BLKS - 1) / RED_BLKS;
    int start = blockIdx.x * chunk;
    int end = start + chunk; if (end > nblk) end = nblk;
    float acc = 0.f;
    for (int r = start + sub; r < end; r += 4)
        acc += partial[(long)r * 64 + ch];
    sred[sub][ch] = acc;
    __syncthreads();
    if (t < 64)
        partial2[(long)blockIdx.x * 64 + t] =
            sred[0][t] + sred[1][t] + sred[2][t] + sred[3][t];
}

// ===== stage 2: fold partial2 + finalize BN scale/shift =====
__global__ void finalize_stats(const float* __restrict__ partial2,
                               const float* __restrict__ g, const float* __restrict__ be,
                               float* __restrict__ ss) {
    __shared__ float sred[4][64];
    __shared__ float sums[64];
    int t = threadIdx.x;           // 256
    int ch = t & 63, sub = t >> 6;
    float acc = 0.f;
    for (int r = sub; r < RED_BLKS; r += 4) acc += partial2[(long)r * 64 + ch];
    sred[sub][ch] = acc;
    __syncthreads();
    if (t < 64) sums[t] = sred[0][t] + sred[1][t] + sred[2][t] + sred[3][t];
    __syncthreads();
    if (t < DH) {
        float mu = sums[t] * (1.0f / NN);
        float var = sums[DH + t] * (1.0f / NN) - mu * mu;
        float sc = g[t] * rsqrtf(var + BN_EPS);
        ss[t] = sc;
        ss[DH + t] = be[t] - mu * sc;
    }
}

// ====== per-graph mean pool of BN(h), affine folded; vectorized uint4 loads ======
__global__ void pool2_aff(const __half* __restrict__ h, const int* __restrict__ gptr,
                          const float* __restrict__ ss, float* __restrict__ emb) {
    int g = blockIdx.x;
    int t = threadIdx.x;           // 64 threads
    int beg = gptr[g], end = gptr[g + 1];
    int sub = t & 3, nt = t >> 2;  // 16 node slots x 4 quarters
    const uint4* hb = (const uint4*)h;
    float acc[8] = {0.f, 0.f, 0.f, 0.f, 0.f, 0.f, 0.f, 0.f};
    for (int n = beg + nt; n < end; n += 16) addh8(acc, hb[(long)n * 4 + sub]);
#pragma unroll
    for (int o = 4; o < 64; o <<= 1) {
#pragma unroll
        for (int i = 0; i < 8; ++i) acc[i] += __shfl_xor(acc[i], o);
    }
    if (t < 4) {
        int c = end - beg;
        int j0 = t * 8;
        float inv = (c > 0) ? 1.0f / (float)c : 0.f;
#pragma unroll
        for (int i = 0; i < 8; ++i) {
            float val = (c > 0) ? ss[j0 + i] * (acc[i] * inv) + ss[DH + j0 + i] : 0.f;
            emb[(long)g * DH + j0 + i] = val;
        }
    }
}

// ================= head: emb -> 16 relu -> 1 sigmoid =================
__global__ void head_kernel(const float* __restrict__ emb,
                            const float* __restrict__ wb, const float* __restrict__ bb,
                            const float* __restrict__ wm, const float* __restrict__ bm,
                            float* __restrict__ out) {
    __shared__ float swb[DH * DB];
    __shared__ float sbb[DB];
    __shared__ float swm[DB];
    int t = threadIdx.x;
    for (int i = t; i < DH * DB; i += blockDim.x) swb[i] = wb[i];
    if (t < DB) { sbb[t] = bb[t]; swm[t] = wm[t]; }
    __syncthreads();

    int g = blockIdx.x * blockDim.x + t;
    if (g >= NG) return;
    float e[DH];
#pragma unroll
    for (int d = 0; d < DH; ++d) e[d] = emb[(long)g * DH + d];
    float acc = bm[0];
#pragma unroll
    for (int j = 0; j < DB; ++j) {
        float z = sbb[j];
#pragma unroll
        for (int d = 0; d < DH; ++d) z += e[d] * swb[d * DB + j];
        z = fmaxf(z, 0.f);
        acc += z * swm[j];
    }
    out[g] = 1.0f / (1.0f + expf(-acc));
}

extern "C" void kernel_launch(void* const* d_in, const int* in_sizes, int n_in,
                              void* d_out, int out_size, void* d_ws, size_t ws_size,
                              hipStream_t stream) {
    const float* x   = (const float*)d_in[0];
    const int*   ei  = (const int*)d_in[1];
    const int*   bat = (const int*)d_in[2];
    const float* w1a = (const float*)d_in[3];  const float* b1a = (const float*)d_in[4];
    const float* w1b = (const float*)d_in[5];  const float* b1b = (const float*)d_in[6];
    const float* g1  = (const float*)d_in[7];  const float* be1 = (const float*)d_in[8];
    const float* w2a = (const float*)d_in[9];  const float* b2a = (const float*)d_in[10];
    const float* w2b = (const float*)d_in[11]; const float* b2b = (const float*)d_in[12];
    const float* g2  = (const float*)d_in[13]; const float* be2 = (const float*)d_in[14];
    const float* w3a = (const float*)d_in[15]; const float* b3a = (const float*)d_in[16];
    const float* w3b = (const float*)d_in[17]; const float* b3b = (const float*)d_in[18];
    const float* g3  = (const float*)d_in[19]; const float* be3 = (const float*)d_in[20];
    const float* wb  = (const float*)d_in[21]; const float* bb  = (const float*)d_in[22];
    const float* wm  = (const float*)d_in[23]; const float* bm  = (const float*)d_in[24];
    float* out = (float*)d_out;

    // ---- workspace layout ----
    char* wsb = (char*)d_ws;
    __half* hbuf16 = (__half*)wsb;                              // NN*DH fp16 = 9.6 MB
    char* regB     = wsb + (size_t)NN * DH * 2;                 // NB*CAP*4 = 16.8 MB (ebuf, then abuf16)
    unsigned* ebuf = (unsigned*)regB;
    __half* abuf16 = (__half*)regB;
    int*   csr_src = (int*)(regB + (size_t)NB * CAP * 4);       // NB*CAP ints
    int*   rbeg    = csr_src + (long)NB * CAP;                  // NN
    int*   rend    = rbeg + NN;                                 // NN
    int*   bcur    = rend + NN;                                 // NB
    int*   gptr    = bcur + NB;                                 // NG+1
    float* emb     = (float*)(gptr + NG + 1);                   // NG*DH
    float* ss1     = emb + (long)NG * DH;                       // 64
    float* ss2     = ss1 + 2 * DH;                              // 64
    float* ss3     = ss2 + 2 * DH;                              // 64
    float* partial2= ss3 + 2 * DH;                              // RED_BLKS*64
    float* partial = partial2 + (long)RED_BLKS * 64;            // FUSED_BLOCKS*64

    const int B = 256;

    // ---- init (bucket cursors + graph bounds) ----
    init_misc<<<(NG + 1 + B - 1) / B, B, 0, stream>>>(bat, bcur, gptr);

    // ---- CSR: block-local binning then per-bucket LDS counting sort ----
    bucket_scatter<<<NSCAT, B, 0, stream>>>(ei, bcur, ebuf);
    bucket_sort<<<NB, B, 0, stream>>>(ebuf, bcur, rbeg, rend, csr_src);

    // ---- layer 1 (fused gather+MLP+stats): x -> hbuf16 ----
    fused_gin6<<<L1_BLOCKS, B, 0, stream>>>(rbeg, rend, csr_src, x,
                                            w1a, b1a, w1b, b1b, hbuf16, partial);
    reduce_partial<<<RED_BLKS, B, 0, stream>>>(partial, L1_BLOCKS, partial2);
    finalize_stats<<<1, B, 0, stream>>>(partial2, g1, be1, ss1);

    // ---- layer 2 (fused): hbuf16 -> abuf16 (ebuf dead now) ----
    fused_gin16<<<FUSED_BLOCKS, B, 0, stream>>>(rbeg, rend, csr_src, hbuf16, ss1,
                                                w2a, b2a, w2b, b2b, abuf16, partial);
    reduce_partial<<<RED_BLKS, B, 0, stream>>>(partial, FUSED_BLOCKS, partial2);
    finalize_stats<<<1, B, 0, stream>>>(partial2, g2, be2, ss2);

    // ---- layer 3 (fused): abuf16 -> hbuf16 ----
    fused_gin16<<<FUSED_BLOCKS, B, 0, stream>>>(rbeg, rend, csr_src, abuf16, ss2,
                                                w3a, b3a, w3b, b3b, hbuf16, partial);
    reduce_partial<<<RED_BLKS, B, 0, stream>>>(partial, FUSED_BLOCKS, partial2);
    finalize_stats<<<1, B, 0, stream>>>(partial2, g3, be3, ss3);

    // ---- pool (BN3 applied inline) + head ----
    pool2_aff<<<NG, 64, 0, stream>>>(hbuf16, gptr, ss3, emb);
    head_kernel<<<(NG + B - 1) / B, B, 0, stream>>>(emb, wb, bb, wm, bm, out);
}

// Round 10
// 238.244 us; speedup vs baseline: 4.0622x; 1.0937x over previous
//
#include <hip/hip_runtime.h>
#include <hip/hip_fp16.h>
#include <math.h>

// Problem constants (match reference)
#define NN 150000
#define NE 2400000
#define NG 1024
#define DIN 6
#define DH 32
#define DB 16
#define BN_EPS 1e-5f

#define FUSED_BLOCKS ((NN + 63) / 64)   // 2344 (all fused layers, 64 nodes/block)
#define RED_BLKS 64                     // stage-1 reduction blocks

// bucket sort params
#define NB 512            // buckets
#define NPB 293           // nodes per bucket (512*293 = 150016 >= NN); NPB < 512 so 9 bits
#define SCH 4096          // edges per scatter block
#define EPB 16            // edges per thread in scatter
#define CAP 8192          // fixed region per bucket (expected ~4690 edges)
#define NSCAT ((NE + SCH - 1) / SCH)  // 586

// inclusive Hillis-Steele scan of 512 ints in LDS with 256 threads
#define SCAN512(scarr, t)                                     \
    for (int off = 1; off < 512; off <<= 1) {                 \
        int v0 = (t >= off) ? scarr[t - off] : 0;             \
        int v1 = scarr[t + 256 - off];                        \
        __syncthreads();                                      \
        if (t >= off) scarr[t] += v0;                         \
        scarr[t + 256] += v1;                                 \
        __syncthreads();                                      \
    }

__device__ inline void addh8(float* a, uint4 v) {
    const __half2* hp = (const __half2*)&v;
#pragma unroll
    for (int i = 0; i < 4; ++i) {
        float2 f = __half22float2(hp[i]);
        a[2 * i] += f.x; a[2 * i + 1] += f.y;
    }
}

// ===== init: bucket cursors + graph bounds + x -> fp16 padded table =====
__global__ void init_cvt(const int* __restrict__ bat, const float* __restrict__ x,
                         int* __restrict__ bcur, int* __restrict__ gptr,
                         __half* __restrict__ x16) {
    int i = blockIdx.x * blockDim.x + threadIdx.x;
    if (i < NB) bcur[i] = i * CAP;
    if (i <= NG) {
        int lo = 0, hi = NN;
        while (lo < hi) {
            int mid = (lo + hi) >> 1;
            if (bat[mid] < i) lo = mid + 1; else hi = mid;
        }
        gptr[i] = lo;
    }
    if (i < NN) {
        const float2* xs = (const float2*)(x + (long)i * DIN);
        float2 p0 = xs[0], p1 = xs[1], p2 = xs[2];
        uint4 v;
        unsigned* vp = (unsigned*)&v;
        __half2 h0 = __floats2half2_rn(p0.x, p0.y);
        __half2 h1 = __floats2half2_rn(p1.x, p1.y);
        __half2 h2 = __floats2half2_rn(p2.x, p2.y);
        __half2 h3 = __floats2half2_rn(0.f, 0.f);
        vp[0] = *(unsigned*)&h0; vp[1] = *(unsigned*)&h1;
        vp[2] = *(unsigned*)&h2; vp[3] = *(unsigned*)&h3;
        ((uint4*)x16)[i] = v;
    }
}

// block-local binning -> packed (src<<9|dst_local) writes into fixed bucket regions
__global__ void bucket_scatter(const int* __restrict__ ei, int* __restrict__ bcur,
                               unsigned* __restrict__ ebuf) {
    __shared__ int hist[NB];
    __shared__ int sc[NB];
    __shared__ int lcur[NB];
    __shared__ int gbase[NB];
    __shared__ unsigned stage[SCH];
    __shared__ unsigned short stageb[SCH];
    int t = threadIdx.x;
    long e0 = (long)blockIdx.x * SCH;
    int s16[EPB], d16[EPB];
    for (int i = t; i < NB; i += 256) hist[i] = 0;
    __syncthreads();
#pragma unroll
    for (int k = 0; k < EPB; ++k) {
        long idx = e0 + k * 256 + t;
        if (idx < NE) {
            s16[k] = ei[idx];
            d16[k] = ei[NE + idx];
            atomicAdd(&hist[d16[k] / NPB], 1);
        } else d16[k] = -1;
    }
    __syncthreads();
    for (int i = t; i < NB; i += 256) sc[i] = hist[i];
    __syncthreads();
    SCAN512(sc, t);
    for (int i = t; i < NB; i += 256) lcur[i] = sc[i] - hist[i];
    __syncthreads();
#pragma unroll
    for (int k = 0; k < EPB; ++k) {
        if (d16[k] >= 0) {
            int b = d16[k] / NPB;
            int p = atomicAdd(&lcur[b], 1);
            stage[p] = ((unsigned)s16[k] << 9) | (unsigned)(d16[k] - b * NPB);
            stageb[p] = (unsigned short)b;
        }
    }
    __syncthreads();
    for (int i = t; i < NB; i += 256) {
        int h = hist[i];
        gbase[i] = h ? atomicAdd(&bcur[i], h) : 0;
    }
    __syncthreads();
    int cnt = (int)((NE - e0) < SCH ? (NE - e0) : SCH);
    for (int i = t; i < cnt; i += 256) {
        int b = stageb[i];
        ebuf[gbase[b] + (i - (sc[b] - hist[b]))] = stage[i];
    }
}

// per-bucket LDS counting sort -> csr_src (fixed stride) + rbeg/rend per node
__global__ void bucket_sort(const unsigned* __restrict__ ebuf, const int* __restrict__ bcur,
                            int* __restrict__ rbeg, int* __restrict__ rend,
                            int* __restrict__ csr_src) {
    __shared__ int deg[NB];
    __shared__ int sc[NB];
    __shared__ int cur[NB];
    __shared__ int srcbuf[CAP];
    int b = blockIdx.x, t = threadIdx.x;
    int node0 = b * NPB;
    int nlocal = (NN - node0) < NPB ? (NN - node0) : NPB;
    int ebase = b * CAP;
    int ecnt = bcur[b] - ebase;
    if (ecnt > CAP) ecnt = CAP;
    for (int i = t; i < NB; i += 256) deg[i] = 0;
    __syncthreads();
    for (int i = t; i < ecnt; i += 256) {
        atomicAdd(&deg[ebuf[ebase + i] & 511u], 1);
    }
    __syncthreads();
    for (int i = t; i < NB; i += 256) sc[i] = deg[i];
    __syncthreads();
    SCAN512(sc, t);
    for (int j = t; j < nlocal; j += 256) {
        int st = sc[j] - deg[j];
        rbeg[node0 + j] = ebase + st;
        rend[node0 + j] = ebase + st + deg[j];
        cur[j] = st;
    }
    __syncthreads();
    for (int i = t; i < ecnt; i += 256) {
        unsigned v = ebuf[ebase + i];
        int p = atomicAdd(&cur[v & 511u], 1);
        srcbuf[p] = (int)(v >> 9);
    }
    __syncthreads();
    for (int i = t; i < ecnt; i += 256) csr_src[ebase + i] = srcbuf[i];
}

// ======== fused layer 1: edge-split gather of x16 (L2-resident) + MLP + stats ========
// 64 nodes / block, 4 threads / node (edge-split), quad-reduce agg.
__global__ void __launch_bounds__(256) fused_gin6(
    const int* __restrict__ rbeg, const int* __restrict__ rend,
    const int* __restrict__ csr_src, const __half* __restrict__ x16,
    const float* __restrict__ w1, const float* __restrict__ b1,
    const float* __restrict__ w2, const float* __restrict__ b2,
    __half* __restrict__ out, float* __restrict__ partial) {
    __shared__ float sw1[DIN * DH];
    __shared__ float sw2[DH * DH];
    __shared__ float sb1[DH];
    __shared__ float sb2[DH];
    __shared__ float bsum[DH];
    __shared__ float bsq[DH];
    int t = threadIdx.x;
    for (int i = t; i < DIN * DH; i += 256) sw1[i] = w1[i];
    for (int i = t; i < DH * DH; i += 256) sw2[i] = w2[i];
    if (t < DH) { sb1[t] = b1[t]; sb2[t] = b2[t]; bsum[t] = 0.f; bsq[t] = 0.f; }
    __syncthreads();

    int nl = t >> 2, sub = t & 3;
    int node = blockIdx.x * 64 + nl;
    bool valid = node < NN;
    int j0 = sub * 8;
    int qb = t & ~3;

    // ---- edge-split gather: thread sub takes edges beg+sub, beg+sub+4, ... ----
    const uint4* xb = (const uint4*)x16;
    float a[8] = {0.f, 0.f, 0.f, 0.f, 0.f, 0.f, 0.f, 0.f};
    int beg = 0, end = 0;
    if (valid) {
        beg = rbeg[node]; end = rend[node];
        if (sub == 0) addh8(a, xb[node]);    // self term once
    }
    for (int e = beg + sub; e < end; e += 4) addh8(a, xb[csr_src[e]]);
    // quad reduce -> every thread holds the full 6-ch (8 slot) agg
#pragma unroll
    for (int i = 0; i < 8; ++i) {
        a[i] += __shfl_xor(a[i], 1);
        a[i] += __shfl_xor(a[i], 2);
    }

    // ---- MLP layer A (IN=6, inputs local): thread computes its 8 outputs ----
    float u[8];
#pragma unroll
    for (int i = 0; i < 8; ++i) {
        int j = j0 + i;
        float acc = sb1[j];
#pragma unroll
        for (int k = 0; k < DIN; ++k) acc += a[k] * sw1[k * DH + j];
        u[i] = fmaxf(acc, 0.f);
    }

    // ---- MLP layer B via quad-shuffle exchange ----
    float r[8];
#pragma unroll
    for (int i = 0; i < 8; ++i) r[i] = sb2[j0 + i];
#pragma unroll
    for (int q = 0; q < 4; ++q) {
#pragma unroll
        for (int i = 0; i < 8; ++i) {
            float uk = __shfl(u[i], qb + q);
            int k = q * 8 + i;
            const float4* w4 = (const float4*)&sw2[k * DH + j0];
            float4 wa = w4[0], wb = w4[1];
            r[0] += uk * wa.x; r[1] += uk * wa.y; r[2] += uk * wa.z; r[3] += uk * wa.w;
            r[4] += uk * wb.x; r[5] += uk * wb.y; r[6] += uk * wb.z; r[7] += uk * wb.w;
        }
    }
#pragma unroll
    for (int i = 0; i < 8; ++i) r[i] = valid ? fmaxf(r[i], 0.f) : 0.f;

    if (valid) {
        uint4 o;
        unsigned* op = (unsigned*)&o;
#pragma unroll
        for (int i = 0; i < 4; ++i) {
            __half2 hh = __floats2half2_rn(r[2 * i], r[2 * i + 1]);
            op[i] = *(unsigned*)&hh;
        }
        ((uint4*)out)[(long)node * 4 + sub] = o;
    }

    // ---- stats ----
    float s[8], q[8];
#pragma unroll
    for (int i = 0; i < 8; ++i) { s[i] = r[i]; q[i] = r[i] * r[i]; }
#pragma unroll
    for (int o = 4; o < 64; o <<= 1) {
#pragma unroll
        for (int i = 0; i < 8; ++i) {
            s[i] += __shfl_xor(s[i], o);
            q[i] += __shfl_xor(q[i], o);
        }
    }
    if ((t & 63) < 4) {
#pragma unroll
        for (int i = 0; i < 8; ++i) {
            atomicAdd(&bsum[j0 + i], s[i]);
            atomicAdd(&bsq[j0 + i], q[i]);
        }
    }
    __syncthreads();
    if (t < 2 * DH) {
        float v = (t < DH) ? bsum[t] : bsq[t - DH];
        partial[(long)blockIdx.x * (2 * DH) + t] = v;
    }
}

// ======== fused layers 2/3 (fp16 h): gather + MLP via quad-shuffle ========
__global__ void __launch_bounds__(256) fused_gin16(
    const int* __restrict__ rbeg, const int* __restrict__ rend,
    const int* __restrict__ csr_src,
    const __half* __restrict__ h, const float* __restrict__ ss,
    const float* __restrict__ w1, const float* __restrict__ b1,
    const float* __restrict__ w2, const float* __restrict__ b2,
    __half* __restrict__ out, float* __restrict__ partial /* [gridDim][64] */) {
    __shared__ float sw1[DH * DH];
    __shared__ float sw2[DH * DH];
    __shared__ float sb1[DH];
    __shared__ float sb2[DH];
    __shared__ float bsum[DH];
    __shared__ float bsq[DH];
    int t = threadIdx.x;
    for (int i = t; i < DH * DH; i += 256) { sw1[i] = w1[i]; sw2[i] = w2[i]; }
    if (t < DH) { sb1[t] = b1[t]; sb2[t] = b2[t]; bsum[t] = 0.f; bsq[t] = 0.f; }
    __syncthreads();

    int nl = t >> 2, sub = t & 3;
    int node = blockIdx.x * 64 + nl;
    bool valid = node < NN;
    int j0 = sub * 8;
    int qb = t & ~3;      // quad base lane (same wave)

    // ---- gather (4 threads/node, 8 fp16 ch each = 16B loads), 4-deep unroll ----
    const uint4* hb = (const uint4*)h;   // node row = 4 uint4
    float a[8] = {0.f, 0.f, 0.f, 0.f, 0.f, 0.f, 0.f, 0.f};
    int beg = 0, end = 0;
    if (valid) {
        beg = rbeg[node]; end = rend[node];
        addh8(a, hb[(long)node * 4 + sub]);     // self term
    }
    int e = beg;
    int nrem = end - beg;
    for (int i = 0; i < (nrem & ~3); i += 4) {
        int s0 = csr_src[e], s1 = csr_src[e + 1], s2 = csr_src[e + 2], s3 = csr_src[e + 3];
        e += 4;
        uint4 v0 = hb[(long)s0 * 4 + sub];
        uint4 v1 = hb[(long)s1 * 4 + sub];
        uint4 v2 = hb[(long)s2 * 4 + sub];
        uint4 v3 = hb[(long)s3 * 4 + sub];
        addh8(a, v0); addh8(a, v1); addh8(a, v2); addh8(a, v3);
    }
    for (; e < end; ++e) addh8(a, hb[(long)csr_src[e] * 4 + sub]);

    // ---- BN affine fold (stays in registers) ----
    float cnt = (float)(end - beg + 1);
#pragma unroll
    for (int i = 0; i < 8; ++i)
        a[i] = a[i] * ss[j0 + i] + cnt * ss[DH + j0 + i];

    // ---- MLP layer A via quad-shuffle exchange ----
    float u[8];
#pragma unroll
    for (int i = 0; i < 8; ++i) u[i] = sb1[j0 + i];
#pragma unroll
    for (int q = 0; q < 4; ++q) {
#pragma unroll
        for (int i = 0; i < 8; ++i) {
            float ak = __shfl(a[i], qb + q);
            int k = q * 8 + i;
            const float4* w4 = (const float4*)&sw1[k * DH + j0];
            float4 wa = w4[0], wb = w4[1];
            u[0] += ak * wa.x; u[1] += ak * wa.y; u[2] += ak * wa.z; u[3] += ak * wa.w;
            u[4] += ak * wb.x; u[5] += ak * wb.y; u[6] += ak * wb.z; u[7] += ak * wb.w;
        }
    }
#pragma unroll
    for (int i = 0; i < 8; ++i) u[i] = fmaxf(u[i], 0.f);

    // ---- MLP layer B via quad-shuffle exchange ----
    float r[8];
#pragma unroll
    for (int i = 0; i < 8; ++i) r[i] = sb2[j0 + i];
#pragma unroll
    for (int q = 0; q < 4; ++q) {
#pragma unroll
        for (int i = 0; i < 8; ++i) {
            float uk = __shfl(u[i], qb + q);
            int k = q * 8 + i;
            const float4* w4 = (const float4*)&sw2[k * DH + j0];
            float4 wa = w4[0], wb = w4[1];
            r[0] += uk * wa.x; r[1] += uk * wa.y; r[2] += uk * wa.z; r[3] += uk * wa.w;
            r[4] += uk * wb.x; r[5] += uk * wb.y; r[6] += uk * wb.z; r[7] += uk * wb.w;
        }
    }
#pragma unroll
    for (int i = 0; i < 8; ++i) r[i] = valid ? fmaxf(r[i], 0.f) : 0.f;

    if (valid) {
        uint4 o;
        unsigned* op = (unsigned*)&o;
#pragma unroll
        for (int i = 0; i < 4; ++i) {
            __half2 hh = __floats2half2_rn(r[2 * i], r[2 * i + 1]);
            op[i] = *(unsigned*)&hh;
        }
        ((uint4*)out)[(long)node * 4 + sub] = o;
    }

    // ---- stats: butterfly over the 16 nodes in this wave, then LDS atomic ----
    float s[8], q[8];
#pragma unroll
    for (int i = 0; i < 8; ++i) { s[i] = r[i]; q[i] = r[i] * r[i]; }
#pragma unroll
    for (int o = 4; o < 64; o <<= 1) {
#pragma unroll
        for (int i = 0; i < 8; ++i) {
            s[i] += __shfl_xor(s[i], o);
            q[i] += __shfl_xor(q[i], o);
        }
    }
    if ((t & 63) < 4) {
#pragma unroll
        for (int i = 0; i < 8; ++i) {
            atomicAdd(&bsum[j0 + i], s[i]);
            atomicAdd(&bsq[j0 + i], q[i]);
        }
    }
    __syncthreads();
    if (t < 2 * DH) {
        float v = (t < DH) ? bsum[t] : bsq[t - DH];
        partial[(long)blockIdx.x * (2 * DH) + t] = v;
    }
}

// ===== stage 1: fold partial[nblk][64] -> partial2[RED_BLKS][64], coalesced =====
__global__ void reduce_partial(const float* __restrict__ partial, int nblk,
                               float* __restrict__ partial2) {
    __shared__ float sred[4][64];
    int t = threadIdx.x;           // 256
    int ch = t & 63, sub = t >> 6;
    int chunk = (nblk + RED_BLKS - 1) / RED_BLKS;
    int start = blockIdx.x * chunk;
    int end = start + chunk; if (end > nblk) end = nblk;
    float acc = 0.f;
    for (int r = start + sub; r < end; r += 4)
        acc += partial[(long)r * 64 + ch];
    sred[sub][ch] = acc;
    __syncthreads();
    if (t < 64)
        partial2[(long)blockIdx.x * 64 + t] =
            sred[0][t] + sred[1][t] + sred[2][t] + sred[3][t];
}

// ===== stage 2: fold partial2 + finalize BN scale/shift =====
__global__ void finalize_stats(const float* __restrict__ partial2,
                               const float* __restrict__ g, const float* __restrict__ be,
                               float* __restrict__ ss) {
    __shared__ float sred[4][64];
    __shared__ float sums[64];
    int t = threadIdx.x;           // 256
    int ch = t & 63, sub = t >> 6;
    float acc = 0.f;
    for (int r = sub; r < RED_BLKS; r += 4) acc += partial2[(long)r * 64 + ch];
    sred[sub][ch] = acc;
    __syncthreads();
    if (t < 64) sums[t] = sred[0][t] + sred[1][t] + sred[2][t] + sred[3][t];
    __syncthreads();
    if (t < DH) {
        float mu = sums[t] * (1.0f / NN);
        float var = sums[DH + t] * (1.0f / NN) - mu * mu;
        float sc = g[t] * rsqrtf(var + BN_EPS);
        ss[t] = sc;
        ss[DH + t] = be[t] - mu * sc;
    }
}

// ====== fused pool(BN affine folded) + head, one block per graph ======
__global__ void pool_head(const __half* __restrict__ h, const int* __restrict__ gptr,
                          const float* __restrict__ ss,
                          const float* __restrict__ wb, const float* __restrict__ bb,
                          const float* __restrict__ wm, const float* __restrict__ bm,
                          float* __restrict__ out) {
    __shared__ float swb[DH * DB];
    __shared__ float sbb[DB];
    __shared__ float swm[DB];
    __shared__ float semb[DH];
    int g = blockIdx.x;
    int t = threadIdx.x;           // 64 threads
    for (int i = t; i < DH * DB; i += 64) swb[i] = wb[i];
    if (t < DB) { sbb[t] = bb[t]; swm[t] = wm[t]; }
    int beg = gptr[g], end = gptr[g + 1];
    int sub = t & 3, nt = t >> 2;  // 16 node slots x 4 quarters
    const uint4* hb = (const uint4*)h;
    float acc[8] = {0.f, 0.f, 0.f, 0.f, 0.f, 0.f, 0.f, 0.f};
    for (int n = beg + nt; n < end; n += 16) addh8(acc, hb[(long)n * 4 + sub]);
#pragma unroll
    for (int o = 4; o < 64; o <<= 1) {
#pragma unroll
        for (int i = 0; i < 8; ++i) acc[i] += __shfl_xor(acc[i], o);
    }
    if (t < 4) {
        int c = end - beg;
        int j0 = t * 8;
        float inv = (c > 0) ? 1.0f / (float)c : 0.f;
#pragma unroll
        for (int i = 0; i < 8; ++i)
            semb[j0 + i] = (c > 0) ? ss[j0 + i] * (acc[i] * inv) + ss[DH + j0 + i] : 0.f;
    }
    __syncthreads();
    float z = 0.f;
    if (t < DB) {
        z = sbb[t];
#pragma unroll
        for (int k = 0; k < DH; ++k) z += semb[k] * swb[k * DB + t];
        z = fmaxf(z, 0.f) * swm[t];
    }
#pragma unroll
    for (int o = 1; o < DB; o <<= 1) z += __shfl_xor(z, o);
    if (t == 0) out[g] = 1.0f / (1.0f + expf(-(z + bm[0])));
}

extern "C" void kernel_launch(void* const* d_in, const int* in_sizes, int n_in,
                              void* d_out, int out_size, void* d_ws, size_t ws_size,
                              hipStream_t stream) {
    const float* x   = (const float*)d_in[0];
    const int*   ei  = (const int*)d_in[1];
    const int*   bat = (const int*)d_in[2];
    const float* w1a = (const float*)d_in[3];  const float* b1a = (const float*)d_in[4];
    const float* w1b = (const float*)d_in[5];  const float* b1b = (const float*)d_in[6];
    const float* g1  = (const float*)d_in[7];  const float* be1 = (const float*)d_in[8];
    const float* w2a = (const float*)d_in[9];  const float* b2a = (const float*)d_in[10];
    const float* w2b = (const float*)d_in[11]; const float* b2b = (const float*)d_in[12];
    const float* g2  = (const float*)d_in[13]; const float* be2 = (const float*)d_in[14];
    const float* w3a = (const float*)d_in[15]; const float* b3a = (const float*)d_in[16];
    const float* w3b = (const float*)d_in[17]; const float* b3b = (const float*)d_in[18];
    const float* g3  = (const float*)d_in[19]; const float* be3 = (const float*)d_in[20];
    const float* wb  = (const float*)d_in[21]; const float* bb  = (const float*)d_in[22];
    const float* wm  = (const float*)d_in[23]; const float* bm  = (const float*)d_in[24];
    float* out = (float*)d_out;

    // ---- workspace layout ----
    char* wsb = (char*)d_ws;
    __half* hbuf16 = (__half*)wsb;                              // NN*DH fp16 = 9.6 MB
    char* regB     = wsb + (size_t)NN * DH * 2;                 // NB*CAP*4 = 16.8 MB (ebuf, then abuf16)
    unsigned* ebuf = (unsigned*)regB;
    __half* abuf16 = (__half*)regB;
    int*   csr_src = (int*)(regB + (size_t)NB * CAP * 4);       // NB*CAP ints
    int*   rbeg    = csr_src + (long)NB * CAP;                  // NN
    int*   rend    = rbeg + NN;                                 // NN
    int*   bcur    = rend + NN;                                 // NB
    int*   gptr    = bcur + NB;                                 // NG+1
    float* ss1     = (float*)(gptr + NG + 1);                   // 64
    float* ss2     = ss1 + 2 * DH;                              // 64
    float* ss3     = ss2 + 2 * DH;                              // 64
    float* partial2= ss3 + 2 * DH;                              // RED_BLKS*64
    float* partial = partial2 + (long)RED_BLKS * 64;            // FUSED_BLOCKS*64
    __half* x16    = (__half*)(partial + (long)FUSED_BLOCKS * 2 * DH); // NN*8 fp16 = 2.4 MB

    const int B = 256;
    int blkN = (NN + B - 1) / B;

    // ---- init (bucket cursors + graph bounds + x16 table) ----
    init_cvt<<<blkN, B, 0, stream>>>(bat, x, bcur, gptr, x16);

    // ---- CSR: block-local binning then per-bucket LDS counting sort ----
    bucket_scatter<<<NSCAT, B, 0, stream>>>(ei, bcur, ebuf);
    bucket_sort<<<NB, B, 0, stream>>>(ebuf, bcur, rbeg, rend, csr_src);

    // ---- layer 1 (fused, L2-resident x16 gathers): -> hbuf16 ----
    fused_gin6<<<FUSED_BLOCKS, B, 0, stream>>>(rbeg, rend, csr_src, x16,
                                               w1a, b1a, w1b, b1b, hbuf16, partial);
    reduce_partial<<<RED_BLKS, B, 0, stream>>>(partial, FUSED_BLOCKS, partial2);
    finalize_stats<<<1, B, 0, stream>>>(partial2, g1, be1, ss1);

    // ---- layer 2 (fused): hbuf16 -> abuf16 (ebuf dead now) ----
    fused_gin16<<<FUSED_BLOCKS, B, 0, stream>>>(rbeg, rend, csr_src, hbuf16, ss1,
                                                w2a, b2a, w2b, b2b, abuf16, partial);
    reduce_partial<<<RED_BLKS, B, 0, stream>>>(partial, FUSED_BLOCKS, partial2);
    finalize_stats<<<1, B, 0, stream>>>(partial2, g2, be2, ss2);

    // ---- layer 3 (fused): abuf16 -> hbuf16 ----
    fused_gin16<<<FUSED_BLOCKS, B, 0, stream>>>(rbeg, rend, csr_src, abuf16, ss2,
                                                w3a, b3a, w3b, b3b, hbuf16, partial);
    reduce_partial<<<RED_BLKS, B, 0, stream>>>(partial, FUSED_BLOCKS, partial2);
    finalize_stats<<<1, B, 0, stream>>>(partial2, g3, be3, ss3);

    // ---- fused pool (BN3 inline) + head ----
    pool_head<<<NG, 64, 0, stream>>>(hbuf16, gptr, ss3, wb, bb, wm, bm, out);
}